// Round 13
// baseline (280.887 us; speedup 1.0000x reference)
//
#include <hip/hip_runtime.h>
#include <hip/hip_bf16.h>

// NeuroMemory (f32 I/O). 11-launch pipeline:
//  megaprep (13-seg cvt: q->qb, pw->pwb aliased in d_out; transpose, bprime,
//  gather3, khvw) ; btot ; S1 GEMM (bf16 split-K) ; reduce+softmax ;
//  writes GEMM ; fused usum+reduce+update ; qproj3 gemm256db ; ggemm (7
//  problems, bf16 both sides) ; attn_es in-place ; attn_w in-place (4 rows/
//  block, reg-preloaded K/V) ; tail gemm256db. Both big GEMMs use the T3/T4
//  2-phase schedule: named dbuf, counted vmcnt(6), raw s_barrier.

using bf = __hip_bfloat16;
using short8v = __attribute__((ext_vector_type(8))) short;
using f32x4  = __attribute__((ext_vector_type(4))) float;

#define GLOAD_LDS16(g, l) __builtin_amdgcn_global_load_lds( \
    (const __attribute__((address_space(1))) void*)(g), \
    (__attribute__((address_space(3))) void*)(l), 16, 0, 0)

__device__ inline float bf2f(unsigned short s) {
    union { unsigned u; float f; } c; c.u = ((unsigned)s) << 16; return c.f;
}
__device__ inline unsigned short f2bu(float x) { // RNE f32->bf16 bits
    union { float f; unsigned u; } c; c.f = x;
    unsigned r = c.u + 0x7FFF + ((c.u >> 16) & 1);
    return (unsigned short)(r >> 16);
}
__device__ inline void storeC(float* p, float v) { *p = v; }
__device__ inline void storeC(bf* p, float v) { *p = __float2bfloat16(v); }

// ---------------------------------------------------------------------------
// 4-wave 128x128 GEMM (write-phase split-K): C = A[M,K] @ B[N,K]^T, partials.
// ---------------------------------------------------------------------------
__global__ __launch_bounds__(256) void gemm_bt(
    const bf* __restrict__ A, int lda,
    const bf* __restrict__ B, int ldb,
    float* __restrict__ part, int M, int N, int K)
{
    __shared__ short As[128 * 64];
    __shared__ short Bs[128 * 64];
    const int nbn = N >> 7;
    const int bm = blockIdx.x / nbn, bn = blockIdx.x % nbn;
    const int t = threadIdx.x;
    const int w = t >> 6, lane = t & 63;
    const int wr = w >> 1, wc = w & 1;
    const int l16 = lane & 15, lhi = lane >> 4;
    const int kc = K / gridDim.y;
    const int kbeg = blockIdx.y * kc, kend = kbeg + kc;

    f32x4 acc[4][4];
    #pragma unroll
    for (int i = 0; i < 4; ++i)
        #pragma unroll
        for (int j = 0; j < 4; ++j) { f32x4 z = {0.f, 0.f, 0.f, 0.f}; acc[i][j] = z; }

    const bf* Arow = A + (size_t)bm * 128 * lda;
    const bf* Brow = B + (size_t)bn * 128 * ldb;

    for (int k0 = kbeg; k0 < kend; k0 += 64) {
        #pragma unroll
        for (int j = 0; j < 4; ++j) {
            int u = (w * 4 + j) * 64 + lane;
            int row = u >> 3, c8 = u & 7;
            int slot = c8 ^ (row & 7);
            GLOAD_LDS16(Brow + (size_t)row * ldb + k0 + slot * 8, &Bs[(w * 4 + j) * 512]);
            GLOAD_LDS16(Arow + (size_t)row * lda + k0 + slot * 8, &As[(w * 4 + j) * 512]);
        }
        __syncthreads();
        #pragma unroll
        for (int kk = 0; kk < 2; ++kk) {
            short8v af[4], bfr[4];
            #pragma unroll
            for (int mt = 0; mt < 4; ++mt) {
                int row = wr * 64 + mt * 16 + l16;
                int slot = (kk * 4 + lhi) ^ (row & 7);
                af[mt] = *(const short8v*)&As[row * 64 + slot * 8];
            }
            #pragma unroll
            for (int nt = 0; nt < 4; ++nt) {
                int row = wc * 64 + nt * 16 + l16;
                int slot = (kk * 4 + lhi) ^ (row & 7);
                bfr[nt] = *(const short8v*)&Bs[row * 64 + slot * 8];
            }
            #pragma unroll
            for (int mt = 0; mt < 4; ++mt)
                #pragma unroll
                for (int nt = 0; nt < 4; ++nt)
                    acc[mt][nt] = __builtin_amdgcn_mfma_f32_16x16x32_bf16(
                        af[mt], bfr[nt], acc[mt][nt], 0, 0, 0);
        }
        __syncthreads();
    }
    #pragma unroll
    for (int mt = 0; mt < 4; ++mt)
        #pragma unroll
        for (int nt = 0; nt < 4; ++nt) {
            int col = bn * 128 + wc * 64 + nt * 16 + l16;
            #pragma unroll
            for (int j = 0; j < 4; ++j) {
                int rowg = bm * 128 + wr * 64 + mt * 16 + lhi * 4 + j;
                part[(size_t)blockIdx.y * M * N + (size_t)rowg * N + col] = acc[mt][nt][j];
            }
        }
}

// ---------------------------------------------------------------------------
// 8-wave 256x128 GEMM, DOUBLE-BUFFERED 2-phase (T3/T4): named buffers,
// raw s_barrier + counted asm vmcnt(6). K multiple of 128. 1 block/CU.
// ---------------------------------------------------------------------------
template <typename CT>
__global__ __launch_bounds__(512) void gemm256db(
    const bf* __restrict__ A, int lda,
    const bf* __restrict__ B, int ldb,
    const float* __restrict__ bias,
    CT* __restrict__ C, int ldc,
    int M, int N, int K)
{
    __shared__ short As0[256 * 64];
    __shared__ short Bs0[128 * 64];
    __shared__ short As1[256 * 64];
    __shared__ short Bs1[128 * 64];
    const int nbn = N >> 7;
    int bid = blockIdx.x;
    bid = (bid & 7) * (gridDim.x >> 3) + (bid >> 3);
    const int bm = bid / nbn, bn = bid % nbn;
    const int t = threadIdx.x;
    const int w = t >> 6, lane = t & 63;
    const int wr = w >> 1, wc = w & 1;
    const int l16 = lane & 15, lhi = lane >> 4;

    f32x4 acc[4][4];
    #pragma unroll
    for (int i = 0; i < 4; ++i)
        #pragma unroll
        for (int j = 0; j < 4; ++j) { f32x4 z = {0.f, 0.f, 0.f, 0.f}; acc[i][j] = z; }

    const bf* Arow = A + (size_t)bm * 256 * lda;
    const bf* Brow = B + (size_t)bn * 128 * ldb;

    auto stage = [&](short* Asd, short* Bsd, int k0) {
        #pragma unroll
        for (int j = 0; j < 2; ++j) {
            int u = t + (j << 9);
            int row = u >> 3, c8 = u & 7;
            int slot = c8 ^ (row & 7);
            GLOAD_LDS16(Brow + (size_t)row * ldb + k0 + slot * 8, &Bsd[(j * 8 + w) * 512]);
        }
        #pragma unroll
        for (int j = 0; j < 4; ++j) {
            int u = t + (j << 9);
            int row = u >> 3, c8 = u & 7;
            int slot = c8 ^ (row & 7);
            GLOAD_LDS16(Arow + (size_t)row * lda + k0 + slot * 8, &Asd[(j * 8 + w) * 512]);
        }
    };
    auto compute = [&](const short* Ass, const short* Bss) {
        #pragma unroll
        for (int kk = 0; kk < 2; ++kk) {
            short8v af[4], bfr[4];
            #pragma unroll
            for (int mt = 0; mt < 4; ++mt) {
                int row = wr * 64 + mt * 16 + l16;
                int slot = (kk * 4 + lhi) ^ (row & 7);
                af[mt] = *(const short8v*)&Ass[row * 64 + slot * 8];
            }
            #pragma unroll
            for (int nt = 0; nt < 4; ++nt) {
                int row = wc * 64 + nt * 16 + l16;
                int slot = (kk * 4 + lhi) ^ (row & 7);
                bfr[nt] = *(const short8v*)&Bss[row * 64 + slot * 8];
            }
            #pragma unroll
            for (int mt = 0; mt < 4; ++mt)
                #pragma unroll
                for (int nt = 0; nt < 4; ++nt)
                    acc[mt][nt] = __builtin_amdgcn_mfma_f32_16x16x32_bf16(
                        af[mt], bfr[nt], acc[mt][nt], 0, 0, 0);
        }
    };

    const int nt_ = K >> 6;
    stage(As0, Bs0, 0);
    stage(As1, Bs1, 64);
    asm volatile("s_waitcnt vmcnt(6)" ::: "memory");
    __builtin_amdgcn_sched_barrier(0);
    __builtin_amdgcn_s_barrier();

    for (int ti = 0; ti < nt_ - 2; ti += 2) {
        compute(As0, Bs0);
        __builtin_amdgcn_s_barrier();
        stage(As0, Bs0, (ti + 2) << 6);
        asm volatile("s_waitcnt vmcnt(6)" ::: "memory");
        __builtin_amdgcn_sched_barrier(0);
        __builtin_amdgcn_s_barrier();
        compute(As1, Bs1);
        __builtin_amdgcn_s_barrier();
        stage(As1, Bs1, (ti + 3) << 6);
        asm volatile("s_waitcnt vmcnt(6)" ::: "memory");
        __builtin_amdgcn_sched_barrier(0);
        __builtin_amdgcn_s_barrier();
    }
    compute(As0, Bs0);
    __builtin_amdgcn_s_barrier();
    asm volatile("s_waitcnt vmcnt(0)" ::: "memory");
    __builtin_amdgcn_sched_barrier(0);
    __builtin_amdgcn_s_barrier();
    compute(As1, Bs1);

    #pragma unroll
    for (int mt = 0; mt < 4; ++mt)
        #pragma unroll
        for (int nt = 0; nt < 4; ++nt) {
            int col = bn * 128 + wc * 64 + nt * 16 + l16;
            float bv = bias ? bias[col] : 0.0f;
            #pragma unroll
            for (int j = 0; j < 4; ++j) {
                int rowg = bm * 256 + wr * 64 + mt * 16 + lhi * 4 + j;
                storeC(&C[(size_t)rowg * ldc + col], acc[mt][nt][j] + bv);
            }
        }
}

// ---------------------------------------------------------------------------
// Grouped GEMM, 7 problems, K=1024, BOTH operands bf16 via global_load_lds,
// fused epilogue: bf16 out (+f32 bias), strided ldo. 256 blocks.
// ---------------------------------------------------------------------------
struct GG { const bf* A; const bf* B; const float* bias; bf* out;
            int lda, ldb, M, N, ldo, xoff; };
struct GG7 { GG g[7]; };

__global__ __launch_bounds__(256) void ggemm(GG7 P)
{
    __shared__ short As[128 * 64];
    __shared__ short Bs[128 * 64];
    const int bid = blockIdx.x;
    int gidx = 0;
    #pragma unroll
    for (int i = 1; i < 7; ++i) if (bid >= P.g[i].xoff) gidx = i;
    const GG d = P.g[gidx];
    const int lb = bid - d.xoff;
    const int nbn = d.N >> 7;
    const int bm = lb / nbn, bn = lb % nbn;
    const int t = threadIdx.x;
    const int w = t >> 6, lane = t & 63;
    const int wr = w >> 1, wc = w & 1;
    const int l16 = lane & 15, lhi = lane >> 4;

    f32x4 acc[4][4];
    #pragma unroll
    for (int i = 0; i < 4; ++i)
        #pragma unroll
        for (int j = 0; j < 4; ++j) { f32x4 z = {0.f, 0.f, 0.f, 0.f}; acc[i][j] = z; }

    const bf* Afrow = d.A + (size_t)bm * 128 * d.lda;
    const bf* Brow  = d.B + (size_t)bn * 128 * d.ldb;

    for (int k0 = 0; k0 < 1024; k0 += 64) {
        #pragma unroll
        for (int j = 0; j < 4; ++j) {
            int u = (w * 4 + j) * 64 + lane;
            int row = u >> 3, c8 = u & 7;
            int slot = c8 ^ (row & 7);
            GLOAD_LDS16(Brow + (size_t)row * d.ldb + k0 + slot * 8, &Bs[(w * 4 + j) * 512]);
            GLOAD_LDS16(Afrow + (size_t)row * d.lda + k0 + slot * 8, &As[(w * 4 + j) * 512]);
        }
        __syncthreads();
        #pragma unroll
        for (int kk = 0; kk < 2; ++kk) {
            short8v af[4], bfr[4];
            #pragma unroll
            for (int mt = 0; mt < 4; ++mt) {
                int row = wr * 64 + mt * 16 + l16;
                int slot = (kk * 4 + lhi) ^ (row & 7);
                af[mt] = *(const short8v*)&As[row * 64 + slot * 8];
            }
            #pragma unroll
            for (int nt = 0; nt < 4; ++nt) {
                int row = wc * 64 + nt * 16 + l16;
                int slot = (kk * 4 + lhi) ^ (row & 7);
                bfr[nt] = *(const short8v*)&Bs[row * 64 + slot * 8];
            }
            #pragma unroll
            for (int mt = 0; mt < 4; ++mt)
                #pragma unroll
                for (int nt = 0; nt < 4; ++nt)
                    acc[mt][nt] = __builtin_amdgcn_mfma_f32_16x16x32_bf16(
                        af[mt], bfr[nt], acc[mt][nt], 0, 0, 0);
        }
        __syncthreads();
    }
    #pragma unroll
    for (int mt = 0; mt < 4; ++mt)
        #pragma unroll
        for (int nt = 0; nt < 4; ++nt) {
            int col = bn * 128 + wc * 64 + nt * 16 + l16;
            float bv = d.bias ? d.bias[col] : 0.0f;
            #pragma unroll
            for (int j = 0; j < 4; ++j) {
                int rowg = bm * 128 + wr * 64 + mt * 16 + lhi * 4 + j;
                d.out[(size_t)rowg * d.ldo + col]
                    = __float2bfloat16(acc[mt][nt][j] + bv);
            }
        }
}

// ---------------------------------------------------------------------------
// Merged e/s attention, IN-PLACE over qcat3/Ocat [8192,3072].
// ---------------------------------------------------------------------------
__global__ __launch_bounds__(512) void attn_es(
    bf* Ocat, const bf* __restrict__ khE, const bf* __restrict__ khS,
    const bf* __restrict__ vTE, const bf* __restrict__ vTS)
{
    __shared__ short Ks[256 * 64];  // reused as P after QK barrier
    __shared__ short Vs[64 * 256];
    const int bank = blockIdx.x >> 10;
    const int lbid = blockIdx.x & 1023;
    const bf* kh  = bank ? khS : khE;
    const bf* vhT = bank ? vTS : vTE;
    bf* QO = Ocat + bank * 1024;
    const int qt = lbid >> 4, head = lbid & 15;
    const int t = threadIdx.x, w = t >> 6, lane = t & 63;
    const int l16 = lane & 15, lhi = lane >> 4;
    const float scale = 0.125f;

    #pragma unroll
    for (int j = 0; j < 4; ++j) {
        int ublk = w * 4 + j;
        int u = ublk * 64 + lane;
        { int row = u >> 3, c8 = u & 7;
          int slot = c8 ^ (row & 7);
          GLOAD_LDS16(kh + (size_t)row * 1024 + head * 64 + slot * 8, &Ks[ublk * 512]); }
        { int row = u >> 5, c16 = u & 31;
          int slot = c16 ^ (row & 7);
          GLOAD_LDS16(vhT + (size_t)(head * 64 + row) * 256 + slot * 8, &Vs[ublk * 512]); }
    }
    const int qr = qt * 128 + w * 16 + l16;
    short8v aq0 = *(const short8v*)(QO + (size_t)qr * 3072 + head * 64 + lhi * 8);
    short8v aq1 = *(const short8v*)(QO + (size_t)qr * 3072 + head * 64 + 32 + lhi * 8);
    __syncthreads();

    f32x4 sc[16];
    #pragma unroll
    for (int nt = 0; nt < 16; ++nt) { f32x4 z = {0.f, 0.f, 0.f, 0.f}; sc[nt] = z; }
    #pragma unroll
    for (int nt = 0; nt < 16; ++nt) {
        int row = nt * 16 + l16;
        #pragma unroll
        for (int kk = 0; kk < 2; ++kk) {
            int slot = (kk * 4 + lhi) ^ (row & 7);
            short8v b = *(const short8v*)&Ks[row * 64 + slot * 8];
            sc[nt] = __builtin_amdgcn_mfma_f32_16x16x32_bf16(kk ? aq1 : aq0, b, sc[nt], 0, 0, 0);
        }
    }
    float inv[4];
    #pragma unroll
    for (int j = 0; j < 4; ++j) {
        float m_ = -1e30f;
        #pragma unroll
        for (int nt = 0; nt < 16; ++nt) m_ = fmaxf(m_, sc[nt][j]);
        #pragma unroll
        for (int off = 8; off; off >>= 1) m_ = fmaxf(m_, __shfl_xor(m_, off));
        float s_ = 0.f;
        #pragma unroll
        for (int nt = 0; nt < 16; ++nt) {
            float e = __expf((sc[nt][j] - m_) * scale);
            sc[nt][j] = e; s_ += e;
        }
        #pragma unroll
        for (int off = 8; off; off >>= 1) s_ += __shfl_xor(s_, off);
        inv[j] = 1.0f / s_;
    }
    __syncthreads();

    char* Pw = (char*)Ks + w * 4096;
    f32x4 oa[4];
    #pragma unroll
    for (int nt = 0; nt < 4; ++nt) { f32x4 z = {0.f, 0.f, 0.f, 0.f}; oa[nt] = z; }
    #pragma unroll
    for (int h = 0; h < 2; ++h) {
        #pragma unroll
        for (int nt = 0; nt < 8; ++nt) {
            int colL = nt * 16 + l16;
            #pragma unroll
            for (int j = 0; j < 4; ++j) {
                int row = lhi * 4 + j;
                *(short*)(Pw + row * 256 + ((colL * 2) ^ ((row & 7) << 4)))
                    = (short)f2bu(sc[h * 8 + nt][j] * inv[j]);
            }
        }
        #pragma unroll
        for (int kk = 0; kk < 4; ++kk) {
            short8v a = *(const short8v*)(Pw + l16 * 256 + (((kk * 32 + lhi * 8) * 2) ^ ((l16 & 7) << 4)));
            #pragma unroll
            for (int nt = 0; nt < 4; ++nt) {
                int row = nt * 16 + l16;
                int m = h * 128 + kk * 32 + lhi * 8;
                short8v b = *(const short8v*)((const char*)Vs + row * 512 + ((m * 2) ^ ((row & 7) << 4)));
                oa[nt] = __builtin_amdgcn_mfma_f32_16x16x32_bf16(a, b, oa[nt], 0, 0, 0);
            }
        }
    }
    #pragma unroll
    for (int nt = 0; nt < 4; ++nt)
        #pragma unroll
        for (int j = 0; j < 4; ++j)
            QO[(size_t)(qt * 128 + w * 16 + lhi * 4 + j) * 3072 + head * 64 + nt * 16 + l16]
                = __float2bfloat16(oa[nt][j]);
}

// ---------------------------------------------------------------------------
// Working-memory attention, IN-PLACE, 4 rows/block, reg-preloaded K/V.
// heads=8, d=128, M=10. 2048 blocks x 256 thr.
// ---------------------------------------------------------------------------
__global__ __launch_bounds__(256) void attn_w(
    bf* QOp, const bf* __restrict__ khw, const bf* __restrict__ vhw)
{
    const int t = threadIdx.x;
    const int head = t >> 5;
    const int dg = head * 128 + (t & 31) * 4;

    ushort4 kv[10], vv[10];
    #pragma unroll
    for (int m = 0; m < 10; ++m) {
        kv[m] = *(const ushort4*)(khw + (size_t)m * 1024 + dg);
        vv[m] = *(const ushort4*)(vhw + (size_t)m * 1024 + dg);
    }
    #pragma unroll
    for (int r = 0; r < 4; ++r) {
        const int bs = blockIdx.x * 4 + r;
        ushort4 qv = *(const ushort4*)(QOp + (size_t)bs * 3072 + dg);
        float q0 = bf2f(qv.x), q1 = bf2f(qv.y), q2 = bf2f(qv.z), q3 = bf2f(qv.w);
        float s[10];
        #pragma unroll
        for (int m = 0; m < 10; ++m) {
            float pr = q0 * bf2f(kv[m].x) + q1 * bf2f(kv[m].y)
                     + q2 * bf2f(kv[m].z) + q3 * bf2f(kv[m].w);
            #pragma unroll
            for (int off = 16; off; off >>= 1) pr += __shfl_xor(pr, off);
            s[m] = pr * 0.08838834764831845f;
        }
        float mx = s[0];
        #pragma unroll
        for (int m = 1; m < 10; ++m) mx = fmaxf(mx, s[m]);
        float pp[10], sum = 0.f;
        #pragma unroll
        for (int m = 0; m < 10; ++m) { pp[m] = __expf(s[m] - mx); sum += pp[m]; }
        float inv = 1.0f / sum;
        float o0 = 0, o1 = 0, o2 = 0, o3 = 0;
        #pragma unroll
        for (int m = 0; m < 10; ++m) {
            o0 += pp[m] * bf2f(vv[m].x); o1 += pp[m] * bf2f(vv[m].y);
            o2 += pp[m] * bf2f(vv[m].z); o3 += pp[m] * bf2f(vv[m].w);
        }
        bf* op = QOp + (size_t)bs * 3072 + dg;
        op[0] = __float2bfloat16(o0 * inv); op[1] = __float2bfloat16(o1 * inv);
        op[2] = __float2bfloat16(o2 * inv); op[3] = __float2bfloat16(o3 * inv);
    }
}

// ---------------------------------------------------------------------------
// MEGAPREP: one launch for all independent prep work.
// blocks [0,20224): 13-segment f32->bf16 cvt (q->qb, pw->pwb in d_out alias)
//        [20224,21248): 4x 1024x1024 transpose+cvt
//        [21248,22016): bprime (3072 wave-dots)
//        [22016,22028): gather3 (bqcat3, 3072)
//        [22028,27148): khvw (20480 wave-dots)
// ---------------------------------------------------------------------------
struct CS { const float* src; bf* dst; int voff; };
struct MP {
    CS cs[13];
    const float* tsrc[4]; bf* tdst[4];
    const float* ow[3]; const float* ob[3]; const float* ib[3];
    float* bp;
    const float* inb_e; const float* inb_s; float* bqcat3;
    const float* wm; const float* inw_w; const float* inb_w;
    bf* khw; bf* vhw;
};

__global__ __launch_bounds__(256) void megaprep(MP P)
{
    __shared__ unsigned short tile[64][65];
    const int bid = blockIdx.x;
    const int t = threadIdx.x;
    if (bid < 20224) {
        int gi = bid * 256 + t;
        int gidx = 0;
        #pragma unroll
        for (int i = 1; i < 13; ++i) if (gi >= P.cs[i].voff) gidx = i;
        int i = (gi - P.cs[gidx].voff) * 4;
        float4 v = *(const float4*)(P.cs[gidx].src + i);
        ushort4 o;
        o.x = f2bu(v.x); o.y = f2bu(v.y); o.z = f2bu(v.z); o.w = f2bu(v.w);
        *(ushort4*)((unsigned short*)P.cs[gidx].dst + i) = o;
    } else if (bid < 21248) {
        int lb = bid - 20224;
        int sel = lb >> 8, bb = lb & 255;
        const float* in = P.tsrc[sel];
        bf* outT = P.tdst[sel];
        int bx = bb & 15, by = bb >> 4;
        int r0 = by * 64, c0 = bx * 64;
        int tr = t >> 4, tc4 = (t & 15) * 4;
        #pragma unroll
        for (int i = 0; i < 4; ++i) {
            int r = tr + i * 16;
            float4 v = *(const float4*)(in + (size_t)(r0 + r) * 1024 + c0 + tc4);
            tile[r][tc4 + 0] = f2bu(v.x); tile[r][tc4 + 1] = f2bu(v.y);
            tile[r][tc4 + 2] = f2bu(v.z); tile[r][tc4 + 3] = f2bu(v.w);
        }
        __syncthreads();
        #pragma unroll
        for (int i = 0; i < 4; ++i) {
            int r = tr + i * 16;
            ushort4 v;
            v.x = tile[tc4 + 0][r]; v.y = tile[tc4 + 1][r];
            v.z = tile[tc4 + 2][r]; v.w = tile[tc4 + 3][r];
            *(ushort4*)((unsigned short*)outT + (size_t)(c0 + r) * 1024 + r0 + tc4) = v;
        }
    } else if (bid < 22016) {
        int g = (bid - 21248) * 4 + (t >> 6);
        int lane = t & 63;
        int bank = g >> 10, j = g & 1023;
        const float* ow = P.ow[bank];
        const float* xx = P.ib[bank] + 2048;
        const float* wrow = ow + (size_t)j * 1024;
        float acc = 0.f;
        #pragma unroll
        for (int cc = 0; cc < 4; ++cc) {
            float4 a = *(const float4*)(wrow + lane * 16 + cc * 4);
            float4 x = *(const float4*)(xx + lane * 16 + cc * 4);
            acc += a.x * x.x + a.y * x.y + a.z * x.z + a.w * x.w;
        }
        #pragma unroll
        for (int off = 32; off; off >>= 1) acc += __shfl_xor(acc, off);
        if (lane == 0) P.bp[g] = acc + P.ob[bank][j];
    } else if (bid < 22028) {
        int i = (bid - 22016) * 256 + t;
        if (i < 1024) P.bqcat3[i] = P.inb_e[i];
        else if (i < 2048) P.bqcat3[i] = P.inb_s[i - 1024];
        else P.bqcat3[i] = P.inb_w[i - 2048];
    } else {
        int o = (bid - 22028) * 4 + (t >> 6);
        int lane = t & 63;
        int sel = o >= 10240;
        int o2 = o - sel * 10240;
        int m = o2 >> 10, c = o2 & 1023;
        const float* wrow = P.inw_w + (size_t)(1024 + sel * 1024 + c) * 1024;
        const float* xrow = P.wm + (size_t)m * 1024;
        float acc = 0.f;
        #pragma unroll
        for (int cc = 0; cc < 4; ++cc) {
            float4 a = *(const float4*)(wrow + lane * 16 + cc * 4);
            float4 x = *(const float4*)(xrow + lane * 16 + cc * 4);
            acc += a.x * x.x + a.y * x.y + a.z * x.z + a.w * x.w;
        }
        #pragma unroll
        for (int off = 32; off; off >>= 1) acc += __shfl_xor(acc, off);
        if (lane == 0) {
            float v = acc + (sel ? 0.f : P.inb_w[1024 + c]);
            (sel ? P.vhw : P.khw)[(size_t)m * 1024 + c] = __float2bfloat16(v);
        }
    }
}

// --------------------------- remaining small kernels ------------------------

__global__ __launch_bounds__(256) void btot_kern(
    const float* __restrict__ bp, const float* __restrict__ pw,
    const float* __restrict__ pb, float* __restrict__ btot)
{
    int j = blockIdx.x * 4 + (threadIdx.x >> 6);
    int lane = threadIdx.x & 63;
    const float* row = pw + (size_t)j * 3072;
    float acc = 0.f;
    #pragma unroll
    for (int it = 0; it < 12; ++it) {
        int c = lane * 4 + it * 256;
        float4 a = *(const float4*)(row + c);
        float4 x = *(const float4*)(bp + c);
        acc += a.x * x.x + a.y * x.y + a.z * x.z + a.w * x.w;
    }
    #pragma unroll
    for (int off = 32; off; off >>= 1) acc += __shfl_xor(acc, off);
    if (lane == 0) btot[j] = acc + pb[j];
}

// reduce 8 S1 partials + softmax + x0.1 -> wT[m][n] (bf16, transposed)
__global__ __launch_bounds__(256) void write_softmax_p(const float* __restrict__ part,
                                                       bf* __restrict__ wT)
{
    const int n = blockIdx.x, m = threadIdx.x;
    float s = 0.f;
    #pragma unroll
    for (int k = 0; k < 8; ++k) s += part[(size_t)k * 262144 + n * 256 + m];
    float mx = s;
    #pragma unroll
    for (int off = 32; off; off >>= 1) mx = fmaxf(mx, __shfl_xor(mx, off));
    __shared__ float red[4], red2[4];
    int w = threadIdx.x >> 6;
    if ((threadIdx.x & 63) == 0) red[w] = mx;
    __syncthreads();
    mx = fmaxf(fmaxf(red[0], red[1]), fmaxf(red[2], red[3]));
    float e = __expf(s - mx);
    float sm = e;
    #pragma unroll
    for (int off = 32; off; off >>= 1) sm += __shfl_xor(sm, off);
    if ((threadIdx.x & 63) == 0) red2[w] = sm;
    __syncthreads();
    sm = red2[0] + red2[1] + red2[2] + red2[3];
    wT[(size_t)m * 1024 + n] = __float2bfloat16(0.1f * e / sm);
}

// FUSED: u[m] reduction from wT row + 8-way writes-partials reduce + update.
// 256 blocks (one m each) x 256 thr (4 h each).
__global__ __launch_bounds__(256) void update_fused(
    const float* __restrict__ epk, const float* __restrict__ epv,
    const bf* __restrict__ wT, const float* __restrict__ part,
    bf* __restrict__ ekb, bf* __restrict__ evb)
{
    __shared__ float red[4];
    const int m = blockIdx.x, t = threadIdx.x;
    // u[m] = (1/1024) * sum_n wT[m*1024 + n]
    ushort4 wv = *(const ushort4*)((const unsigned short*)wT + (size_t)m * 1024 + t * 4);
    float s = bf2f(wv.x) + bf2f(wv.y) + bf2f(wv.z) + bf2f(wv.w);
    #pragma unroll
    for (int off = 32; off; off >>= 1) s += __shfl_xor(s, off);
    if ((t & 63) == 0) red[t >> 6] = s;
    __syncthreads();
    float f = 1.0f - (red[0] + red[1] + red[2] + red[3]) * (1.0f / 1024.0f);
    // 4 h per thread
    int base = m * 1024 + t * 4;
    float4 wr = *(const float4*)(part + base);
    #pragma unroll
    for (int k = 1; k < 8; ++k) {
        float4 v = *(const float4*)(part + (size_t)k * 262144 + base);
        wr.x += v.x; wr.y += v.y; wr.z += v.z; wr.w += v.w;
    }
    const float sc = 1.0f / 1024.0f;
    float4 pk = *(const float4*)(epk + base);
    float4 pv = *(const float4*)(epv + base);
    ushort4 ok, ov;
    ok.x = f2bu(pk.x * f + wr.x * sc); ok.y = f2bu(pk.y * f + wr.y * sc);
    ok.z = f2bu(pk.z * f + wr.z * sc); ok.w = f2bu(pk.w * f + wr.w * sc);
    ov.x = f2bu(pv.x * f + wr.x * sc); ov.y = f2bu(pv.y * f + wr.y * sc);
    ov.z = f2bu(pv.z * f + wr.z * sc); ov.w = f2bu(pv.w * f + wr.w * sc);
    *(ushort4*)((unsigned short*)ekb + base) = ok;
    *(ushort4*)((unsigned short*)evb + base) = ov;
}

// ---------------------------------------------------------------------------
extern "C" void kernel_launch(void* const* d_in, const int* in_sizes, int n_in,
                              void* d_out, int out_size, void* d_ws, size_t ws_size,
                              hipStream_t stream)
{
    const float* q     = (const float*)d_in[0];
    const float* data  = (const float*)d_in[1];
    const float* epk   = (const float*)d_in[2];
    const float* epv   = (const float*)d_in[3];
    const float* smk   = (const float*)d_in[4];
    const float* smv   = (const float*)d_in[5];
    const float* wm    = (const float*)d_in[6];
    const float* inw_e = (const float*)d_in[7];  const float* inb_e = (const float*)d_in[8];
    const float* ow_e  = (const float*)d_in[9];  const float* ob_e  = (const float*)d_in[10];
    const float* inw_s = (const float*)d_in[11]; const float* inb_s = (const float*)d_in[12];
    const float* ow_s  = (const float*)d_in[13]; const float* ob_s  = (const float*)d_in[14];
    const float* inw_w = (const float*)d_in[15]; const float* inb_w = (const float*)d_in[16];
    const float* ow_w  = (const float*)d_in[17]; const float* ob_w  = (const float*)d_in[18];
    const float* pw    = (const float*)d_in[19]; const float* pb    = (const float*)d_in[20];
    float* out  = (float*)d_out;
    float* part = (float*)d_out;                       // write-phase partials [0, 8.4 MB)
    bf* qb  = (bf*)((char*)d_out + 8388608);           // q bf16 [8.4, 25.2 MB)
    bf* pwb = (bf*)((char*)d_out + 25165824);          // pw bf16 [25.2, 31.5 MB)

    char* p = (char*)d_ws;
    auto alloc = [&](size_t bytes) -> char* {
        char* r = p; p += (bytes + 255) & ~(size_t)255; return r;
    };
    float* u      = (float*)alloc(256 * 4);
    float* bp     = (float*)alloc(3072 * 4);
    float* btot   = (float*)alloc(1024 * 4);
    float* bqcat3 = (float*)alloc(3072 * 4);
    bf* wT     = (bf*)alloc(256 * 1024 * 2);
    bf* dT     = (bf*)alloc((size_t)1024 * 1024 * 2);
    bf* datab  = (bf*)alloc((size_t)1024 * 1024 * 2);
    bf* epkb   = (bf*)alloc(256 * 1024 * 2);
    bf* smkb   = (bf*)alloc(256 * 1024 * 2);
    bf* smvb   = (bf*)alloc(256 * 1024 * 2);
    bf* ekb    = (bf*)alloc(256 * 1024 * 2);
    bf* evb    = (bf*)alloc(256 * 1024 * 2);
    bf* khE    = (bf*)alloc(256 * 1024 * 2);
    bf* khS    = (bf*)alloc(256 * 1024 * 2);
    bf* vTE    = (bf*)alloc((size_t)1024 * 256 * 2);
    bf* vTS    = (bf*)alloc((size_t)1024 * 256 * 2);
    bf* khw    = (bf*)alloc(10 * 1024 * 2);
    bf* vhw    = (bf*)alloc(10 * 1024 * 2);
    bf* Wall   = (bf*)alloc((size_t)3072 * 1024 * 2); // [Wq_e; Wq_s; Wq_w]
    bf* WkE    = (bf*)alloc((size_t)1024 * 1024 * 2);
    bf* WkS    = (bf*)alloc((size_t)1024 * 1024 * 2);
    bf* WvE    = (bf*)alloc((size_t)1024 * 1024 * 2);
    bf* WvS    = (bf*)alloc((size_t)1024 * 1024 * 2);
    bf* owT0   = (bf*)alloc((size_t)1024 * 1024 * 2);
    bf* owT1   = (bf*)alloc((size_t)1024 * 1024 * 2);
    bf* owT2   = (bf*)alloc((size_t)1024 * 1024 * 2);
    bf* Gcat   = (bf*)alloc((size_t)1024 * 3072 * 2);
    bf* Ocat   = (bf*)alloc((size_t)8192 * 3072 * 2); // qcat3 -> attn in-place -> tail A
    if ((size_t)(p - (char*)d_ws) > ws_size) return;
    (void)u;

    // ---- launch 1: megaprep ----
    {
        MP P;
        CS cs[13] = { {q, qb, 0},
                      {epk,  epkb, 2097152}, {smv, smvb, 2162688},
                      {inw_e, Wall, 2228224},
                      {inw_s, Wall + (size_t)1024 * 1024, 2490368},
                      {inw_w, Wall + (size_t)2048 * 1024, 2752512},
                      {inw_e + (size_t)1024 * 1024, WkE, 3014656},
                      {inw_s + (size_t)1024 * 1024, WkS, 3276800},
                      {data, datab, 3538944},
                      {pw, pwb, 3801088},
                      {smk, smkb, 4587520},
                      {inw_e + (size_t)2048 * 1024, WvE, 4653056},
                      {inw_s + (size_t)2048 * 1024, WvS, 4915200} };
        for (int i = 0; i < 13; ++i) P.cs[i] = cs[i];
        P.tsrc[0] = data; P.tdst[0] = dT;
        P.tsrc[1] = ow_e; P.tdst[1] = owT0;
        P.tsrc[2] = ow_s; P.tdst[2] = owT1;
        P.tsrc[3] = ow_w; P.tdst[3] = owT2;
        P.ow[0] = ow_e; P.ow[1] = ow_s; P.ow[2] = ow_w;
        P.ob[0] = ob_e; P.ob[1] = ob_s; P.ob[2] = ob_w;
        P.ib[0] = inb_e; P.ib[1] = inb_s; P.ib[2] = inb_w;
        P.bp = bp;
        P.inb_e = inb_e; P.inb_s = inb_s; P.bqcat3 = bqcat3;
        P.wm = wm; P.inw_w = inw_w; P.inb_w = inb_w;
        P.khw = khw; P.vhw = vhw;
        megaprep<<<27148, 256, 0, stream>>>(P);
    }
    // ---- launch 2: btot (needs bp) ----
    btot_kern<<<256, 256, 0, stream>>>(bp, pw, pb, btot);

    // ---- write phase (partials in d_out[0, 8.4 MB)) ----
    gemm_bt<<<dim3(16, 8), 256, 0, stream>>>(datab, 1024, epkb, 1024, part, 1024, 256, 1024);
    write_softmax_p<<<1024, 256, 0, stream>>>(part, wT);
    gemm_bt<<<dim3(16, 8), 256, 0, stream>>>(wT, 1024, dT, 1024, part, 256, 1024, 1024);
    update_fused<<<256, 256, 0, stream>>>(epk, epv, wT, part, ekb, evb);

    // ---- merged q-projection: qcat3 = qb @ Wall^T + bqcat3 -> Ocat ----
    gemm256db<bf><<<768, 512, 0, stream>>>(
        qb, 1024, Wall, 1024, bqcat3, Ocat, 3072, 8192, 3072, 1024);

    // ---- grouped GEMM, bf16 both sides, fused epilogue (7 problems) ----
    {
        GG7 G = {{
            { ekb,        WkE,  inb_e + 1024, khE,         1024, 1024,  256, 1024, 1024, 0   },
            { smkb,       WkS,  inb_s + 1024, khS,         1024, 1024,  256, 1024, 1024, 16  },
            { WvE,        evb,  nullptr,      vTE,         1024, 1024, 1024,  256,  256, 32  },
            { WvS,        smvb, nullptr,      vTS,         1024, 1024, 1024,  256,  256, 48  },
            { pwb + 0,    owT0, nullptr,      Gcat + 0,    3072, 1024, 1024, 1024, 3072, 64  },
            { pwb + 1024, owT1, nullptr,      Gcat + 1024, 3072, 1024, 1024, 1024, 3072, 128 },
            { pwb + 2048, owT2, nullptr,      Gcat + 2048, 3072, 1024, 1024, 1024, 3072, 192 },
        }};
        ggemm<<<256, 256, 0, stream>>>(G);
    }

    // ---- attentions, in-place over Ocat ----
    attn_es<<<2048, 512, 0, stream>>>(Ocat, khE, khS, vTE, vTS);
    attn_w<<<2048, 256, 0, stream>>>(Ocat + 2048, khw, vhw);

    // ---- fused tail: double-buffered 2-phase schedule ----
    gemm256db<float><<<256, 512, 0, stream>>>(
        Ocat, 3072, Gcat, 3072, btot, out, 1024, 8192, 1024, 3072);
}

// Round 14
// 266.369 us; speedup vs baseline: 1.0545x; 1.0545x over previous
//
#include <hip/hip_runtime.h>
#include <hip/hip_bf16.h>

// NeuroMemory (f32 I/O). 11-launch pipeline:
//  megaprep (13-seg cvt: q->qb, pw->pwb aliased in d_out; transpose, bprime,
//  gather3, khvw) ; btot ; S1 GEMM ; reduce+softmax ; writes GEMM ; fused
//  usum+reduce+update ; qproj3 gemm256 (single-buf, 3 blocks/CU) ; ggemm ;
//  attn_es in-place ; attn_w in-place ; tail gemm256db (dbuf 2-phase,
//  counted vmcnt(6) -- wins ONLY at 1 block/CU grids).

using bf = __hip_bfloat16;
using short8v = __attribute__((ext_vector_type(8))) short;
using f32x4  = __attribute__((ext_vector_type(4))) float;

#define GLOAD_LDS16(g, l) __builtin_amdgcn_global_load_lds( \
    (const __attribute__((address_space(1))) void*)(g), \
    (__attribute__((address_space(3))) void*)(l), 16, 0, 0)

__device__ inline float bf2f(unsigned short s) {
    union { unsigned u; float f; } c; c.u = ((unsigned)s) << 16; return c.f;
}
__device__ inline unsigned short f2bu(float x) { // RNE f32->bf16 bits
    union { float f; unsigned u; } c; c.f = x;
    unsigned r = c.u + 0x7FFF + ((c.u >> 16) & 1);
    return (unsigned short)(r >> 16);
}
__device__ inline void storeC(float* p, float v) { *p = v; }
__device__ inline void storeC(bf* p, float v) { *p = __float2bfloat16(v); }

// ---------------------------------------------------------------------------
// 4-wave 128x128 GEMM (write-phase split-K): C = A[M,K] @ B[N,K]^T, partials.
// ---------------------------------------------------------------------------
__global__ __launch_bounds__(256) void gemm_bt(
    const bf* __restrict__ A, int lda,
    const bf* __restrict__ B, int ldb,
    float* __restrict__ part, int M, int N, int K)
{
    __shared__ short As[128 * 64];
    __shared__ short Bs[128 * 64];
    const int nbn = N >> 7;
    const int bm = blockIdx.x / nbn, bn = blockIdx.x % nbn;
    const int t = threadIdx.x;
    const int w = t >> 6, lane = t & 63;
    const int wr = w >> 1, wc = w & 1;
    const int l16 = lane & 15, lhi = lane >> 4;
    const int kc = K / gridDim.y;
    const int kbeg = blockIdx.y * kc, kend = kbeg + kc;

    f32x4 acc[4][4];
    #pragma unroll
    for (int i = 0; i < 4; ++i)
        #pragma unroll
        for (int j = 0; j < 4; ++j) { f32x4 z = {0.f, 0.f, 0.f, 0.f}; acc[i][j] = z; }

    const bf* Arow = A + (size_t)bm * 128 * lda;
    const bf* Brow = B + (size_t)bn * 128 * ldb;

    for (int k0 = kbeg; k0 < kend; k0 += 64) {
        #pragma unroll
        for (int j = 0; j < 4; ++j) {
            int u = (w * 4 + j) * 64 + lane;
            int row = u >> 3, c8 = u & 7;
            int slot = c8 ^ (row & 7);
            GLOAD_LDS16(Brow + (size_t)row * ldb + k0 + slot * 8, &Bs[(w * 4 + j) * 512]);
            GLOAD_LDS16(Arow + (size_t)row * lda + k0 + slot * 8, &As[(w * 4 + j) * 512]);
        }
        __syncthreads();
        #pragma unroll
        for (int kk = 0; kk < 2; ++kk) {
            short8v af[4], bfr[4];
            #pragma unroll
            for (int mt = 0; mt < 4; ++mt) {
                int row = wr * 64 + mt * 16 + l16;
                int slot = (kk * 4 + lhi) ^ (row & 7);
                af[mt] = *(const short8v*)&As[row * 64 + slot * 8];
            }
            #pragma unroll
            for (int nt = 0; nt < 4; ++nt) {
                int row = wc * 64 + nt * 16 + l16;
                int slot = (kk * 4 + lhi) ^ (row & 7);
                bfr[nt] = *(const short8v*)&Bs[row * 64 + slot * 8];
            }
            #pragma unroll
            for (int mt = 0; mt < 4; ++mt)
                #pragma unroll
                for (int nt = 0; nt < 4; ++nt)
                    acc[mt][nt] = __builtin_amdgcn_mfma_f32_16x16x32_bf16(
                        af[mt], bfr[nt], acc[mt][nt], 0, 0, 0);
        }
        __syncthreads();
    }
    #pragma unroll
    for (int mt = 0; mt < 4; ++mt)
        #pragma unroll
        for (int nt = 0; nt < 4; ++nt) {
            int col = bn * 128 + wc * 64 + nt * 16 + l16;
            #pragma unroll
            for (int j = 0; j < 4; ++j) {
                int rowg = bm * 128 + wr * 64 + mt * 16 + lhi * 4 + j;
                part[(size_t)blockIdx.y * M * N + (size_t)rowg * N + col] = acc[mt][nt][j];
            }
        }
}

// ---------------------------------------------------------------------------
// 8-wave 256x128 GEMM, single-buffered (for multi-block/CU grids: qproj3).
// ---------------------------------------------------------------------------
template <typename CT>
__global__ __launch_bounds__(512) void gemm256(
    const bf* __restrict__ A, int lda,
    const bf* __restrict__ B, int ldb,
    const float* __restrict__ bias,
    CT* __restrict__ C, int ldc,
    int M, int N, int K)
{
    __shared__ short As[256 * 64];
    __shared__ short Bs[128 * 64];
    const int nbn = N >> 7;
    int bid = blockIdx.x;
    bid = (bid & 7) * (gridDim.x >> 3) + (bid >> 3);
    const int bm = bid / nbn, bn = bid % nbn;
    const int t = threadIdx.x;
    const int w = t >> 6, lane = t & 63;
    const int wr = w >> 1, wc = w & 1;
    const int l16 = lane & 15, lhi = lane >> 4;

    f32x4 acc[4][4];
    #pragma unroll
    for (int i = 0; i < 4; ++i)
        #pragma unroll
        for (int j = 0; j < 4; ++j) { f32x4 z = {0.f, 0.f, 0.f, 0.f}; acc[i][j] = z; }

    const bf* Arow = A + (size_t)bm * 256 * lda;
    const bf* Brow = B + (size_t)bn * 128 * ldb;

    for (int k0 = 0; k0 < K; k0 += 64) {
        #pragma unroll
        for (int j = 0; j < 2; ++j) {
            int u = t + (j << 9);
            int row = u >> 3, c8 = u & 7;
            int slot = c8 ^ (row & 7);
            GLOAD_LDS16(Brow + (size_t)row * ldb + k0 + slot * 8, &Bs[(j * 8 + w) * 512]);
        }
        #pragma unroll
        for (int j = 0; j < 4; ++j) {
            int u = t + (j << 9);
            int row = u >> 3, c8 = u & 7;
            int slot = c8 ^ (row & 7);
            GLOAD_LDS16(Arow + (size_t)row * lda + k0 + slot * 8, &As[(j * 8 + w) * 512]);
        }
        __syncthreads();
        #pragma unroll
        for (int kk = 0; kk < 2; ++kk) {
            short8v af[4], bfr[4];
            #pragma unroll
            for (int mt = 0; mt < 4; ++mt) {
                int row = wr * 64 + mt * 16 + l16;
                int slot = (kk * 4 + lhi) ^ (row & 7);
                af[mt] = *(const short8v*)&As[row * 64 + slot * 8];
            }
            #pragma unroll
            for (int nt = 0; nt < 4; ++nt) {
                int row = wc * 64 + nt * 16 + l16;
                int slot = (kk * 4 + lhi) ^ (row & 7);
                bfr[nt] = *(const short8v*)&Bs[row * 64 + slot * 8];
            }
            #pragma unroll
            for (int mt = 0; mt < 4; ++mt)
                #pragma unroll
                for (int nt = 0; nt < 4; ++nt)
                    acc[mt][nt] = __builtin_amdgcn_mfma_f32_16x16x32_bf16(
                        af[mt], bfr[nt], acc[mt][nt], 0, 0, 0);
        }
        __syncthreads();
    }
    #pragma unroll
    for (int mt = 0; mt < 4; ++mt)
        #pragma unroll
        for (int nt = 0; nt < 4; ++nt) {
            int col = bn * 128 + wc * 64 + nt * 16 + l16;
            float bv = bias ? bias[col] : 0.0f;
            #pragma unroll
            for (int j = 0; j < 4; ++j) {
                int rowg = bm * 256 + wr * 64 + mt * 16 + lhi * 4 + j;
                storeC(&C[(size_t)rowg * ldc + col], acc[mt][nt][j] + bv);
            }
        }
}

// ---------------------------------------------------------------------------
// 8-wave 256x128 GEMM, DOUBLE-BUFFERED 2-phase (for 1-block/CU grids: tail).
// Named buffers, raw s_barrier + counted asm vmcnt(6). K multiple of 128.
// ---------------------------------------------------------------------------
template <typename CT>
__global__ __launch_bounds__(512) void gemm256db(
    const bf* __restrict__ A, int lda,
    const bf* __restrict__ B, int ldb,
    const float* __restrict__ bias,
    CT* __restrict__ C, int ldc,
    int M, int N, int K)
{
    __shared__ short As0[256 * 64];
    __shared__ short Bs0[128 * 64];
    __shared__ short As1[256 * 64];
    __shared__ short Bs1[128 * 64];
    const int nbn = N >> 7;
    int bid = blockIdx.x;
    bid = (bid & 7) * (gridDim.x >> 3) + (bid >> 3);
    const int bm = bid / nbn, bn = bid % nbn;
    const int t = threadIdx.x;
    const int w = t >> 6, lane = t & 63;
    const int wr = w >> 1, wc = w & 1;
    const int l16 = lane & 15, lhi = lane >> 4;

    f32x4 acc[4][4];
    #pragma unroll
    for (int i = 0; i < 4; ++i)
        #pragma unroll
        for (int j = 0; j < 4; ++j) { f32x4 z = {0.f, 0.f, 0.f, 0.f}; acc[i][j] = z; }

    const bf* Arow = A + (size_t)bm * 256 * lda;
    const bf* Brow = B + (size_t)bn * 128 * ldb;

    auto stage = [&](short* Asd, short* Bsd, int k0) {
        #pragma unroll
        for (int j = 0; j < 2; ++j) {
            int u = t + (j << 9);
            int row = u >> 3, c8 = u & 7;
            int slot = c8 ^ (row & 7);
            GLOAD_LDS16(Brow + (size_t)row * ldb + k0 + slot * 8, &Bsd[(j * 8 + w) * 512]);
        }
        #pragma unroll
        for (int j = 0; j < 4; ++j) {
            int u = t + (j << 9);
            int row = u >> 3, c8 = u & 7;
            int slot = c8 ^ (row & 7);
            GLOAD_LDS16(Arow + (size_t)row * lda + k0 + slot * 8, &Asd[(j * 8 + w) * 512]);
        }
    };
    auto compute = [&](const short* Ass, const short* Bss) {
        #pragma unroll
        for (int kk = 0; kk < 2; ++kk) {
            short8v af[4], bfr[4];
            #pragma unroll
            for (int mt = 0; mt < 4; ++mt) {
                int row = wr * 64 + mt * 16 + l16;
                int slot = (kk * 4 + lhi) ^ (row & 7);
                af[mt] = *(const short8v*)&Ass[row * 64 + slot * 8];
            }
            #pragma unroll
            for (int nt = 0; nt < 4; ++nt) {
                int row = wc * 64 + nt * 16 + l16;
                int slot = (kk * 4 + lhi) ^ (row & 7);
                bfr[nt] = *(const short8v*)&Bss[row * 64 + slot * 8];
            }
            #pragma unroll
            for (int mt = 0; mt < 4; ++mt)
                #pragma unroll
                for (int nt = 0; nt < 4; ++nt)
                    acc[mt][nt] = __builtin_amdgcn_mfma_f32_16x16x32_bf16(
                        af[mt], bfr[nt], acc[mt][nt], 0, 0, 0);
        }
    };

    const int nt_ = K >> 6;
    stage(As0, Bs0, 0);
    stage(As1, Bs1, 64);
    asm volatile("s_waitcnt vmcnt(6)" ::: "memory");
    __builtin_amdgcn_sched_barrier(0);
    __builtin_amdgcn_s_barrier();

    for (int ti = 0; ti < nt_ - 2; ti += 2) {
        compute(As0, Bs0);
        __builtin_amdgcn_s_barrier();
        stage(As0, Bs0, (ti + 2) << 6);
        asm volatile("s_waitcnt vmcnt(6)" ::: "memory");
        __builtin_amdgcn_sched_barrier(0);
        __builtin_amdgcn_s_barrier();
        compute(As1, Bs1);
        __builtin_amdgcn_s_barrier();
        stage(As1, Bs1, (ti + 3) << 6);
        asm volatile("s_waitcnt vmcnt(6)" ::: "memory");
        __builtin_amdgcn_sched_barrier(0);
        __builtin_amdgcn_s_barrier();
    }
    compute(As0, Bs0);
    __builtin_amdgcn_s_barrier();
    asm volatile("s_waitcnt vmcnt(0)" ::: "memory");
    __builtin_amdgcn_sched_barrier(0);
    __builtin_amdgcn_s_barrier();
    compute(As1, Bs1);

    #pragma unroll
    for (int mt = 0; mt < 4; ++mt)
        #pragma unroll
        for (int nt = 0; nt < 4; ++nt) {
            int col = bn * 128 + wc * 64 + nt * 16 + l16;
            float bv = bias ? bias[col] : 0.0f;
            #pragma unroll
            for (int j = 0; j < 4; ++j) {
                int rowg = bm * 256 + wr * 64 + mt * 16 + lhi * 4 + j;
                storeC(&C[(size_t)rowg * ldc + col], acc[mt][nt][j] + bv);
            }
        }
}

// ---------------------------------------------------------------------------
// Grouped GEMM, 7 problems, K=1024, BOTH operands bf16 via global_load_lds,
// fused epilogue: bf16 out (+f32 bias), strided ldo. 256 blocks.
// ---------------------------------------------------------------------------
struct GG { const bf* A; const bf* B; const float* bias; bf* out;
            int lda, ldb, M, N, ldo, xoff; };
struct GG7 { GG g[7]; };

__global__ __launch_bounds__(256) void ggemm(GG7 P)
{
    __shared__ short As[128 * 64];
    __shared__ short Bs[128 * 64];
    const int bid = blockIdx.x;
    int gidx = 0;
    #pragma unroll
    for (int i = 1; i < 7; ++i) if (bid >= P.g[i].xoff) gidx = i;
    const GG d = P.g[gidx];
    const int lb = bid - d.xoff;
    const int nbn = d.N >> 7;
    const int bm = lb / nbn, bn = lb % nbn;
    const int t = threadIdx.x;
    const int w = t >> 6, lane = t & 63;
    const int wr = w >> 1, wc = w & 1;
    const int l16 = lane & 15, lhi = lane >> 4;

    f32x4 acc[4][4];
    #pragma unroll
    for (int i = 0; i < 4; ++i)
        #pragma unroll
        for (int j = 0; j < 4; ++j) { f32x4 z = {0.f, 0.f, 0.f, 0.f}; acc[i][j] = z; }

    const bf* Afrow = d.A + (size_t)bm * 128 * d.lda;
    const bf* Brow  = d.B + (size_t)bn * 128 * d.ldb;

    for (int k0 = 0; k0 < 1024; k0 += 64) {
        #pragma unroll
        for (int j = 0; j < 4; ++j) {
            int u = (w * 4 + j) * 64 + lane;
            int row = u >> 3, c8 = u & 7;
            int slot = c8 ^ (row & 7);
            GLOAD_LDS16(Brow + (size_t)row * d.ldb + k0 + slot * 8, &Bs[(w * 4 + j) * 512]);
            GLOAD_LDS16(Afrow + (size_t)row * d.lda + k0 + slot * 8, &As[(w * 4 + j) * 512]);
        }
        __syncthreads();
        #pragma unroll
        for (int kk = 0; kk < 2; ++kk) {
            short8v af[4], bfr[4];
            #pragma unroll
            for (int mt = 0; mt < 4; ++mt) {
                int row = wr * 64 + mt * 16 + l16;
                int slot = (kk * 4 + lhi) ^ (row & 7);
                af[mt] = *(const short8v*)&As[row * 64 + slot * 8];
            }
            #pragma unroll
            for (int nt = 0; nt < 4; ++nt) {
                int row = wc * 64 + nt * 16 + l16;
                int slot = (kk * 4 + lhi) ^ (row & 7);
                bfr[nt] = *(const short8v*)&Bs[row * 64 + slot * 8];
            }
            #pragma unroll
            for (int mt = 0; mt < 4; ++mt)
                #pragma unroll
                for (int nt = 0; nt < 4; ++nt)
                    acc[mt][nt] = __builtin_amdgcn_mfma_f32_16x16x32_bf16(
                        af[mt], bfr[nt], acc[mt][nt], 0, 0, 0);
        }
        __syncthreads();
    }
    #pragma unroll
    for (int mt = 0; mt < 4; ++mt)
        #pragma unroll
        for (int nt = 0; nt < 4; ++nt) {
            int col = bn * 128 + wc * 64 + nt * 16 + l16;
            float bv = d.bias ? d.bias[col] : 0.0f;
            #pragma unroll
            for (int j = 0; j < 4; ++j) {
                int rowg = bm * 128 + wr * 64 + mt * 16 + lhi * 4 + j;
                d.out[(size_t)rowg * d.ldo + col]
                    = __float2bfloat16(acc[mt][nt][j] + bv);
            }
        }
}

// ---------------------------------------------------------------------------
// Merged e/s attention, IN-PLACE over qcat3/Ocat [8192,3072].
// ---------------------------------------------------------------------------
__global__ __launch_bounds__(512) void attn_es(
    bf* Ocat, const bf* __restrict__ khE, const bf* __restrict__ khS,
    const bf* __restrict__ vTE, const bf* __restrict__ vTS)
{
    __shared__ short Ks[256 * 64];  // reused as P after QK barrier
    __shared__ short Vs[64 * 256];
    const int bank = blockIdx.x >> 10;
    const int lbid = blockIdx.x & 1023;
    const bf* kh  = bank ? khS : khE;
    const bf* vhT = bank ? vTS : vTE;
    bf* QO = Ocat + bank * 1024;
    const int qt = lbid >> 4, head = lbid & 15;
    const int t = threadIdx.x, w = t >> 6, lane = t & 63;
    const int l16 = lane & 15, lhi = lane >> 4;
    const float scale = 0.125f;

    #pragma unroll
    for (int j = 0; j < 4; ++j) {
        int ublk = w * 4 + j;
        int u = ublk * 64 + lane;
        { int row = u >> 3, c8 = u & 7;
          int slot = c8 ^ (row & 7);
          GLOAD_LDS16(kh + (size_t)row * 1024 + head * 64 + slot * 8, &Ks[ublk * 512]); }
        { int row = u >> 5, c16 = u & 31;
          int slot = c16 ^ (row & 7);
          GLOAD_LDS16(vhT + (size_t)(head * 64 + row) * 256 + slot * 8, &Vs[ublk * 512]); }
    }
    const int qr = qt * 128 + w * 16 + l16;
    short8v aq0 = *(const short8v*)(QO + (size_t)qr * 3072 + head * 64 + lhi * 8);
    short8v aq1 = *(const short8v*)(QO + (size_t)qr * 3072 + head * 64 + 32 + lhi * 8);
    __syncthreads();

    f32x4 sc[16];
    #pragma unroll
    for (int nt = 0; nt < 16; ++nt) { f32x4 z = {0.f, 0.f, 0.f, 0.f}; sc[nt] = z; }
    #pragma unroll
    for (int nt = 0; nt < 16; ++nt) {
        int row = nt * 16 + l16;
        #pragma unroll
        for (int kk = 0; kk < 2; ++kk) {
            int slot = (kk * 4 + lhi) ^ (row & 7);
            short8v b = *(const short8v*)&Ks[row * 64 + slot * 8];
            sc[nt] = __builtin_amdgcn_mfma_f32_16x16x32_bf16(kk ? aq1 : aq0, b, sc[nt], 0, 0, 0);
        }
    }
    float inv[4];
    #pragma unroll
    for (int j = 0; j < 4; ++j) {
        float m_ = -1e30f;
        #pragma unroll
        for (int nt = 0; nt < 16; ++nt) m_ = fmaxf(m_, sc[nt][j]);
        #pragma unroll
        for (int off = 8; off; off >>= 1) m_ = fmaxf(m_, __shfl_xor(m_, off));
        float s_ = 0.f;
        #pragma unroll
        for (int nt = 0; nt < 16; ++nt) {
            float e = __expf((sc[nt][j] - m_) * scale);
            sc[nt][j] = e; s_ += e;
        }
        #pragma unroll
        for (int off = 8; off; off >>= 1) s_ += __shfl_xor(s_, off);
        inv[j] = 1.0f / s_;
    }
    __syncthreads();

    char* Pw = (char*)Ks + w * 4096;
    f32x4 oa[4];
    #pragma unroll
    for (int nt = 0; nt < 4; ++nt) { f32x4 z = {0.f, 0.f, 0.f, 0.f}; oa[nt] = z; }
    #pragma unroll
    for (int h = 0; h < 2; ++h) {
        #pragma unroll
        for (int nt = 0; nt < 8; ++nt) {
            int colL = nt * 16 + l16;
            #pragma unroll
            for (int j = 0; j < 4; ++j) {
                int row = lhi * 4 + j;
                *(short*)(Pw + row * 256 + ((colL * 2) ^ ((row & 7) << 4)))
                    = (short)f2bu(sc[h * 8 + nt][j] * inv[j]);
            }
        }
        #pragma unroll
        for (int kk = 0; kk < 4; ++kk) {
            short8v a = *(const short8v*)(Pw + l16 * 256 + (((kk * 32 + lhi * 8) * 2) ^ ((l16 & 7) << 4)));
            #pragma unroll
            for (int nt = 0; nt < 4; ++nt) {
                int row = nt * 16 + l16;
                int m = h * 128 + kk * 32 + lhi * 8;
                short8v b = *(const short8v*)((const char*)Vs + row * 512 + ((m * 2) ^ ((row & 7) << 4)));
                oa[nt] = __builtin_amdgcn_mfma_f32_16x16x32_bf16(a, b, oa[nt], 0, 0, 0);
            }
        }
    }
    #pragma unroll
    for (int nt = 0; nt < 4; ++nt)
        #pragma unroll
        for (int j = 0; j < 4; ++j)
            QO[(size_t)(qt * 128 + w * 16 + lhi * 4 + j) * 3072 + head * 64 + nt * 16 + l16]
                = __float2bfloat16(oa[nt][j]);
}

// ---------------------------------------------------------------------------
// Working-memory attention, IN-PLACE, 4 rows/block, reg-preloaded K/V.
// ---------------------------------------------------------------------------
__global__ __launch_bounds__(256) void attn_w(
    bf* QOp, const bf* __restrict__ khw, const bf* __restrict__ vhw)
{
    const int t = threadIdx.x;
    const int head = t >> 5;
    const int dg = head * 128 + (t & 31) * 4;

    ushort4 kv[10], vv[10];
    #pragma unroll
    for (int m = 0; m < 10; ++m) {
        kv[m] = *(const ushort4*)(khw + (size_t)m * 1024 + dg);
        vv[m] = *(const ushort4*)(vhw + (size_t)m * 1024 + dg);
    }
    #pragma unroll
    for (int r = 0; r < 4; ++r) {
        const int bs = blockIdx.x * 4 + r;
        ushort4 qv = *(const ushort4*)(QOp + (size_t)bs * 3072 + dg);
        float q0 = bf2f(qv.x), q1 = bf2f(qv.y), q2 = bf2f(qv.z), q3 = bf2f(qv.w);
        float s[10];
        #pragma unroll
        for (int m = 0; m < 10; ++m) {
            float pr = q0 * bf2f(kv[m].x) + q1 * bf2f(kv[m].y)
                     + q2 * bf2f(kv[m].z) + q3 * bf2f(kv[m].w);
            #pragma unroll
            for (int off = 16; off; off >>= 1) pr += __shfl_xor(pr, off);
            s[m] = pr * 0.08838834764831845f;
        }
        float mx = s[0];
        #pragma unroll
        for (int m = 1; m < 10; ++m) mx = fmaxf(mx, s[m]);
        float pp[10], sum = 0.f;
        #pragma unroll
        for (int m = 0; m < 10; ++m) { pp[m] = __expf(s[m] - mx); sum += pp[m]; }
        float inv = 1.0f / sum;
        float o0 = 0, o1 = 0, o2 = 0, o3 = 0;
        #pragma unroll
        for (int m = 0; m < 10; ++m) {
            o0 += pp[m] * bf2f(vv[m].x); o1 += pp[m] * bf2f(vv[m].y);
            o2 += pp[m] * bf2f(vv[m].z); o3 += pp[m] * bf2f(vv[m].w);
        }
        bf* op = QOp + (size_t)bs * 3072 + dg;
        op[0] = __float2bfloat16(o0 * inv); op[1] = __float2bfloat16(o1 * inv);
        op[2] = __float2bfloat16(o2 * inv); op[3] = __float2bfloat16(o3 * inv);
    }
}

// ---------------------------------------------------------------------------
// MEGAPREP: one launch for all independent prep work.
// blocks [0,20224): 13-segment f32->bf16 cvt (q->qb, pw->pwb in d_out alias)
//        [20224,21248): 4x 1024x1024 transpose+cvt
//        [21248,22016): bprime (3072 wave-dots)
//        [22016,22028): gather3 (bqcat3, 3072)
//        [22028,27148): khvw (20480 wave-dots)
// ---------------------------------------------------------------------------
struct CS { const float* src; bf* dst; int voff; };
struct MP {
    CS cs[13];
    const float* tsrc[4]; bf* tdst[4];
    const float* ow[3]; const float* ob[3]; const float* ib[3];
    float* bp;
    const float* inb_e; const float* inb_s; float* bqcat3;
    const float* wm; const float* inw_w; const float* inb_w;
    bf* khw; bf* vhw;
};

__global__ __launch_bounds__(256) void megaprep(MP P)
{
    __shared__ unsigned short tile[64][65];
    const int bid = blockIdx.x;
    const int t = threadIdx.x;
    if (bid < 20224) {
        int gi = bid * 256 + t;
        int gidx = 0;
        #pragma unroll
        for (int i = 1; i < 13; ++i) if (gi >= P.cs[i].voff) gidx = i;
        int i = (gi - P.cs[gidx].voff) * 4;
        float4 v = *(const float4*)(P.cs[gidx].src + i);
        ushort4 o;
        o.x = f2bu(v.x); o.y = f2bu(v.y); o.z = f2bu(v.z); o.w = f2bu(v.w);
        *(ushort4*)((unsigned short*)P.cs[gidx].dst + i) = o;
    } else if (bid < 21248) {
        int lb = bid - 20224;
        int sel = lb >> 8, bb = lb & 255;
        const float* in = P.tsrc[sel];
        bf* outT = P.tdst[sel];
        int bx = bb & 15, by = bb >> 4;
        int r0 = by * 64, c0 = bx * 64;
        int tr = t >> 4, tc4 = (t & 15) * 4;
        #pragma unroll
        for (int i = 0; i < 4; ++i) {
            int r = tr + i * 16;
            float4 v = *(const float4*)(in + (size_t)(r0 + r) * 1024 + c0 + tc4);
            tile[r][tc4 + 0] = f2bu(v.x); tile[r][tc4 + 1] = f2bu(v.y);
            tile[r][tc4 + 2] = f2bu(v.z); tile[r][tc4 + 3] = f2bu(v.w);
        }
        __syncthreads();
        #pragma unroll
        for (int i = 0; i < 4; ++i) {
            int r = tr + i * 16;
            ushort4 v;
            v.x = tile[tc4 + 0][r]; v.y = tile[tc4 + 1][r];
            v.z = tile[tc4 + 2][r]; v.w = tile[tc4 + 3][r];
            *(ushort4*)((unsigned short*)outT + (size_t)(c0 + r) * 1024 + r0 + tc4) = v;
        }
    } else if (bid < 22016) {
        int g = (bid - 21248) * 4 + (t >> 6);
        int lane = t & 63;
        int bank = g >> 10, j = g & 1023;
        const float* ow = P.ow[bank];
        const float* xx = P.ib[bank] + 2048;
        const float* wrow = ow + (size_t)j * 1024;
        float acc = 0.f;
        #pragma unroll
        for (int cc = 0; cc < 4; ++cc) {
            float4 a = *(const float4*)(wrow + lane * 16 + cc * 4);
            float4 x = *(const float4*)(xx + lane * 16 + cc * 4);
            acc += a.x * x.x + a.y * x.y + a.z * x.z + a.w * x.w;
        }
        #pragma unroll
        for (int off = 32; off; off >>= 1) acc += __shfl_xor(acc, off);
        if (lane == 0) P.bp[g] = acc + P.ob[bank][j];
    } else if (bid < 22028) {
        int i = (bid - 22016) * 256 + t;
        if (i < 1024) P.bqcat3[i] = P.inb_e[i];
        else if (i < 2048) P.bqcat3[i] = P.inb_s[i - 1024];
        else P.bqcat3[i] = P.inb_w[i - 2048];
    } else {
        int o = (bid - 22028) * 4 + (t >> 6);
        int lane = t & 63;
        int sel = o >= 10240;
        int o2 = o - sel * 10240;
        int m = o2 >> 10, c = o2 & 1023;
        const float* wrow = P.inw_w + (size_t)(1024 + sel * 1024 + c) * 1024;
        const float* xrow = P.wm + (size_t)m * 1024;
        float acc = 0.f;
        #pragma unroll
        for (int cc = 0; cc < 4; ++cc) {
            float4 a = *(const float4*)(wrow + lane * 16 + cc * 4);
            float4 x = *(const float4*)(xrow + lane * 16 + cc * 4);
            acc += a.x * x.x + a.y * x.y + a.z * x.z + a.w * x.w;
        }
        #pragma unroll
        for (int off = 32; off; off >>= 1) acc += __shfl_xor(acc, off);
        if (lane == 0) {
            float v = acc + (sel ? 0.f : P.inb_w[1024 + c]);
            (sel ? P.vhw : P.khw)[(size_t)m * 1024 + c] = __float2bfloat16(v);
        }
    }
}

// --------------------------- remaining small kernels ------------------------

__global__ __launch_bounds__(256) void btot_kern(
    const float* __restrict__ bp, const float* __restrict__ pw,
    const float* __restrict__ pb, float* __restrict__ btot)
{
    int j = blockIdx.x * 4 + (threadIdx.x >> 6);
    int lane = threadIdx.x & 63;
    const float* row = pw + (size_t)j * 3072;
    float acc = 0.f;
    #pragma unroll
    for (int it = 0; it < 12; ++it) {
        int c = lane * 4 + it * 256;
        float4 a = *(const float4*)(row + c);
        float4 x = *(const float4*)(bp + c);
        acc += a.x * x.x + a.y * x.y + a.z * x.z + a.w * x.w;
    }
    #pragma unroll
    for (int off = 32; off; off >>= 1) acc += __shfl_xor(acc, off);
    if (lane == 0) btot[j] = acc + pb[j];
}

// reduce 8 S1 partials + softmax + x0.1 -> wT[m][n] (bf16, transposed)
__global__ __launch_bounds__(256) void write_softmax_p(const float* __restrict__ part,
                                                       bf* __restrict__ wT)
{
    const int n = blockIdx.x, m = threadIdx.x;
    float s = 0.f;
    #pragma unroll
    for (int k = 0; k < 8; ++k) s += part[(size_t)k * 262144 + n * 256 + m];
    float mx = s;
    #pragma unroll
    for (int off = 32; off; off >>= 1) mx = fmaxf(mx, __shfl_xor(mx, off));
    __shared__ float red[4], red2[4];
    int w = threadIdx.x >> 6;
    if ((threadIdx.x & 63) == 0) red[w] = mx;
    __syncthreads();
    mx = fmaxf(fmaxf(red[0], red[1]), fmaxf(red[2], red[3]));
    float e = __expf(s - mx);
    float sm = e;
    #pragma unroll
    for (int off = 32; off; off >>= 1) sm += __shfl_xor(sm, off);
    if ((threadIdx.x & 63) == 0) red2[w] = sm;
    __syncthreads();
    sm = red2[0] + red2[1] + red2[2] + red2[3];
    wT[(size_t)m * 1024 + n] = __float2bfloat16(0.1f * e / sm);
}

// FUSED: u[m] reduction from wT row + 8-way writes-partials reduce + update.
__global__ __launch_bounds__(256) void update_fused(
    const float* __restrict__ epk, const float* __restrict__ epv,
    const bf* __restrict__ wT, const float* __restrict__ part,
    bf* __restrict__ ekb, bf* __restrict__ evb)
{
    __shared__ float red[4];
    const int m = blockIdx.x, t = threadIdx.x;
    ushort4 wv = *(const ushort4*)((const unsigned short*)wT + (size_t)m * 1024 + t * 4);
    float s = bf2f(wv.x) + bf2f(wv.y) + bf2f(wv.z) + bf2f(wv.w);
    #pragma unroll
    for (int off = 32; off; off >>= 1) s += __shfl_xor(s, off);
    if ((t & 63) == 0) red[t >> 6] = s;
    __syncthreads();
    float f = 1.0f - (red[0] + red[1] + red[2] + red[3]) * (1.0f / 1024.0f);
    int base = m * 1024 + t * 4;
    float4 wr = *(const float4*)(part + base);
    #pragma unroll
    for (int k = 1; k < 8; ++k) {
        float4 v = *(const float4*)(part + (size_t)k * 262144 + base);
        wr.x += v.x; wr.y += v.y; wr.z += v.z; wr.w += v.w;
    }
    const float sc = 1.0f / 1024.0f;
    float4 pk = *(const float4*)(epk + base);
    float4 pv = *(const float4*)(epv + base);
    ushort4 ok, ov;
    ok.x = f2bu(pk.x * f + wr.x * sc); ok.y = f2bu(pk.y * f + wr.y * sc);
    ok.z = f2bu(pk.z * f + wr.z * sc); ok.w = f2bu(pk.w * f + wr.w * sc);
    ov.x = f2bu(pv.x * f + wr.x * sc); ov.y = f2bu(pv.y * f + wr.y * sc);
    ov.z = f2bu(pv.z * f + wr.z * sc); ov.w = f2bu(pv.w * f + wr.w * sc);
    *(ushort4*)((unsigned short*)ekb + base) = ok;
    *(ushort4*)((unsigned short*)evb + base) = ov;
}

// ---------------------------------------------------------------------------
extern "C" void kernel_launch(void* const* d_in, const int* in_sizes, int n_in,
                              void* d_out, int out_size, void* d_ws, size_t ws_size,
                              hipStream_t stream)
{
    const float* q     = (const float*)d_in[0];
    const float* data  = (const float*)d_in[1];
    const float* epk   = (const float*)d_in[2];
    const float* epv   = (const float*)d_in[3];
    const float* smk   = (const float*)d_in[4];
    const float* smv   = (const float*)d_in[5];
    const float* wm    = (const float*)d_in[6];
    const float* inw_e = (const float*)d_in[7];  const float* inb_e = (const float*)d_in[8];
    const float* ow_e  = (const float*)d_in[9];  const float* ob_e  = (const float*)d_in[10];
    const float* inw_s = (const float*)d_in[11]; const float* inb_s = (const float*)d_in[12];
    const float* ow_s  = (const float*)d_in[13]; const float* ob_s  = (const float*)d_in[14];
    const float* inw_w = (const float*)d_in[15]; const float* inb_w = (const float*)d_in[16];
    const float* ow_w  = (const float*)d_in[17]; const float* ob_w  = (const float*)d_in[18];
    const float* pw    = (const float*)d_in[19]; const float* pb    = (const float*)d_in[20];
    float* out  = (float*)d_out;
    float* part = (float*)d_out;                       // write-phase partials [0, 8.4 MB)
    bf* qb  = (bf*)((char*)d_out + 8388608);           // q bf16 [8.4, 25.2 MB)
    bf* pwb = (bf*)((char*)d_out + 25165824);          // pw bf16 [25.2, 31.5 MB)

    char* p = (char*)d_ws;
    auto alloc = [&](size_t bytes) -> char* {
        char* r = p; p += (bytes + 255) & ~(size_t)255; return r;
    };
    float* bp     = (float*)alloc(3072 * 4);
    float* btot   = (float*)alloc(1024 * 4);
    float* bqcat3 = (float*)alloc(3072 * 4);
    bf* wT     = (bf*)alloc(256 * 1024 * 2);
    bf* dT     = (bf*)alloc((size_t)1024 * 1024 * 2);
    bf* datab  = (bf*)alloc((size_t)1024 * 1024 * 2);
    bf* epkb   = (bf*)alloc(256 * 1024 * 2);
    bf* smkb   = (bf*)alloc(256 * 1024 * 2);
    bf* smvb   = (bf*)alloc(256 * 1024 * 2);
    bf* ekb    = (bf*)alloc(256 * 1024 * 2);
    bf* evb    = (bf*)alloc(256 * 1024 * 2);
    bf* khE    = (bf*)alloc(256 * 1024 * 2);
    bf* khS    = (bf*)alloc(256 * 1024 * 2);
    bf* vTE    = (bf*)alloc((size_t)1024 * 256 * 2);
    bf* vTS    = (bf*)alloc((size_t)1024 * 256 * 2);
    bf* khw    = (bf*)alloc(10 * 1024 * 2);
    bf* vhw    = (bf*)alloc(10 * 1024 * 2);
    bf* Wall   = (bf*)alloc((size_t)3072 * 1024 * 2); // [Wq_e; Wq_s; Wq_w]
    bf* WkE    = (bf*)alloc((size_t)1024 * 1024 * 2);
    bf* WkS    = (bf*)alloc((size_t)1024 * 1024 * 2);
    bf* WvE    = (bf*)alloc((size_t)1024 * 1024 * 2);
    bf* WvS    = (bf*)alloc((size_t)1024 * 1024 * 2);
    bf* owT0   = (bf*)alloc((size_t)1024 * 1024 * 2);
    bf* owT1   = (bf*)alloc((size_t)1024 * 1024 * 2);
    bf* owT2   = (bf*)alloc((size_t)1024 * 1024 * 2);
    bf* Gcat   = (bf*)alloc((size_t)1024 * 3072 * 2);
    bf* Ocat   = (bf*)alloc((size_t)8192 * 3072 * 2); // qcat3 -> attn in-place -> tail A
    if ((size_t)(p - (char*)d_ws) > ws_size) return;

    // ---- launch 1: megaprep ----
    {
        MP P;
        CS cs[13] = { {q, qb, 0},
                      {epk,  epkb, 2097152}, {smv, smvb, 2162688},
                      {inw_e, Wall, 2228224},
                      {inw_s, Wall + (size_t)1024 * 1024, 2490368},
                      {inw_w, Wall + (size_t)2048 * 1024, 2752512},
                      {inw_e + (size_t)1024 * 1024, WkE, 3014656},
                      {inw_s + (size_t)1024 * 1024, WkS, 3276800},
                      {data, datab, 3538944},
                      {pw, pwb, 3801088},
                      {smk, smkb, 4587520},
                      {inw_e + (size_t)2048 * 1024, WvE, 4653056},
                      {inw_s + (size_t)2048 * 1024, WvS, 4915200} };
        for (int i = 0; i < 13; ++i) P.cs[i] = cs[i];
        P.tsrc[0] = data; P.tdst[0] = dT;
        P.tsrc[1] = ow_e; P.tdst[1] = owT0;
        P.tsrc[2] = ow_s; P.tdst[2] = owT1;
        P.tsrc[3] = ow_w; P.tdst[3] = owT2;
        P.ow[0] = ow_e; P.ow[1] = ow_s; P.ow[2] = ow_w;
        P.ob[0] = ob_e; P.ob[1] = ob_s; P.ob[2] = ob_w;
        P.ib[0] = inb_e; P.ib[1] = inb_s; P.ib[2] = inb_w;
        P.bp = bp;
        P.inb_e = inb_e; P.inb_s = inb_s; P.bqcat3 = bqcat3;
        P.wm = wm; P.inw_w = inw_w; P.inb_w = inb_w;
        P.khw = khw; P.vhw = vhw;
        megaprep<<<27148, 256, 0, stream>>>(P);
    }
    // ---- launch 2: btot (needs bp) ----
    btot_kern<<<256, 256, 0, stream>>>(bp, pw, pb, btot);

    // ---- write phase (partials in d_out[0, 8.4 MB)) ----
    gemm_bt<<<dim3(16, 8), 256, 0, stream>>>(datab, 1024, epkb, 1024, part, 1024, 256, 1024);
    write_softmax_p<<<1024, 256, 0, stream>>>(part, wT);
    gemm_bt<<<dim3(16, 8), 256, 0, stream>>>(wT, 1024, dT, 1024, part, 256, 1024, 1024);
    update_fused<<<256, 256, 0, stream>>>(epk, epv, wT, part, ekb, evb);

    // ---- merged q-projection: qcat3 = qb @ Wall^T + bqcat3 -> Ocat ----
    gemm256<bf><<<768, 512, 0, stream>>>(
        qb, 1024, Wall, 1024, bqcat3, Ocat, 3072, 8192, 3072, 1024);

    // ---- grouped GEMM, bf16 both sides, fused epilogue (7 problems) ----
    {
        GG7 G = {{
            { ekb,        WkE,  inb_e + 1024, khE,         1024, 1024,  256, 1024, 1024, 0   },
            { smkb,       WkS,  inb_s + 1024, khS,         1024, 1024,  256, 1024, 1024, 16  },
            { WvE,        evb,  nullptr,      vTE,         1024, 1024, 1024,  256,  256, 32  },
            { WvS,        smvb, nullptr,      vTS,         1024, 1024, 1024,  256,  256, 48  },
            { pwb + 0,    owT0, nullptr,      Gcat + 0,    3072, 1024, 1024, 1024, 3072, 64  },
            { pwb + 1024, owT1, nullptr,      Gcat + 1024, 3072, 1024, 1024, 1024, 3072, 128 },
            { pwb + 2048, owT2, nullptr,      Gcat + 2048, 3072, 1024, 1024, 1024, 3072, 192 },
        }};
        ggemm<<<256, 256, 0, stream>>>(G);
    }

    // ---- attentions, in-place over Ocat ----
    attn_es<<<2048, 512, 0, stream>>>(Ocat, khE, khS, vTE, vTS);
    attn_w<<<2048, 256, 0, stream>>>(Ocat + 2048, khw, vhw);

    // ---- fused tail: double-buffered 2-phase schedule (1 block/CU grid) ----
    gemm256db<float><<<256, 512, 0, stream>>>(
        Ocat, 3072, Gcat, 3072, btot, out, 1024, 8192, 1024, 3072);
}

// Round 15
// 262.348 us; speedup vs baseline: 1.0707x; 1.0153x over previous
//
#include <hip/hip_runtime.h>
#include <hip/hip_bf16.h>

// NeuroMemory (f32 I/O). 11-launch pipeline:
//  megaprep (13-seg cvt: q->qb, pw->pwb aliased in d_out; transpose, bprime,
//  gather3, khvw) ; btot ; S1 GEMM ; reduce+softmax ; writes GEMM ; fused
//  usum+reduce+update ; qproj3 gemm256 (single-buf, 3 blocks/CU) ; ggemm
//  (dbuf 2-phase, vmcnt(8), 1 block/CU) ; attn_es in-place ; attn_w in-place ;
//  tail gemm256db (dbuf 2-phase, vmcnt(6), 1 block/CU).
// Rule (R13/R14 A/B): counted-vmcnt dbuf pays ONLY at 1 block/CU; at multi-
// block/CU occupancy single-buffer + TLP wins.

using bf = __hip_bfloat16;
using short8v = __attribute__((ext_vector_type(8))) short;
using f32x4  = __attribute__((ext_vector_type(4))) float;

#define GLOAD_LDS16(g, l) __builtin_amdgcn_global_load_lds( \
    (const __attribute__((address_space(1))) void*)(g), \
    (__attribute__((address_space(3))) void*)(l), 16, 0, 0)

__device__ inline float bf2f(unsigned short s) {
    union { unsigned u; float f; } c; c.u = ((unsigned)s) << 16; return c.f;
}
__device__ inline unsigned short f2bu(float x) { // RNE f32->bf16 bits
    union { float f; unsigned u; } c; c.f = x;
    unsigned r = c.u + 0x7FFF + ((c.u >> 16) & 1);
    return (unsigned short)(r >> 16);
}
__device__ inline void storeC(float* p, float v) { *p = v; }
__device__ inline void storeC(bf* p, float v) { *p = __float2bfloat16(v); }

// ---------------------------------------------------------------------------
// 4-wave 128x128 GEMM (write-phase split-K): C = A[M,K] @ B[N,K]^T, partials.
// ---------------------------------------------------------------------------
__global__ __launch_bounds__(256) void gemm_bt(
    const bf* __restrict__ A, int lda,
    const bf* __restrict__ B, int ldb,
    float* __restrict__ part, int M, int N, int K)
{
    __shared__ short As[128 * 64];
    __shared__ short Bs[128 * 64];
    const int nbn = N >> 7;
    const int bm = blockIdx.x / nbn, bn = blockIdx.x % nbn;
    const int t = threadIdx.x;
    const int w = t >> 6, lane = t & 63;
    const int wr = w >> 1, wc = w & 1;
    const int l16 = lane & 15, lhi = lane >> 4;
    const int kc = K / gridDim.y;
    const int kbeg = blockIdx.y * kc, kend = kbeg + kc;

    f32x4 acc[4][4];
    #pragma unroll
    for (int i = 0; i < 4; ++i)
        #pragma unroll
        for (int j = 0; j < 4; ++j) { f32x4 z = {0.f, 0.f, 0.f, 0.f}; acc[i][j] = z; }

    const bf* Arow = A + (size_t)bm * 128 * lda;
    const bf* Brow = B + (size_t)bn * 128 * ldb;

    for (int k0 = kbeg; k0 < kend; k0 += 64) {
        #pragma unroll
        for (int j = 0; j < 4; ++j) {
            int u = (w * 4 + j) * 64 + lane;
            int row = u >> 3, c8 = u & 7;
            int slot = c8 ^ (row & 7);
            GLOAD_LDS16(Brow + (size_t)row * ldb + k0 + slot * 8, &Bs[(w * 4 + j) * 512]);
            GLOAD_LDS16(Arow + (size_t)row * lda + k0 + slot * 8, &As[(w * 4 + j) * 512]);
        }
        __syncthreads();
        #pragma unroll
        for (int kk = 0; kk < 2; ++kk) {
            short8v af[4], bfr[4];
            #pragma unroll
            for (int mt = 0; mt < 4; ++mt) {
                int row = wr * 64 + mt * 16 + l16;
                int slot = (kk * 4 + lhi) ^ (row & 7);
                af[mt] = *(const short8v*)&As[row * 64 + slot * 8];
            }
            #pragma unroll
            for (int nt = 0; nt < 4; ++nt) {
                int row = wc * 64 + nt * 16 + l16;
                int slot = (kk * 4 + lhi) ^ (row & 7);
                bfr[nt] = *(const short8v*)&Bs[row * 64 + slot * 8];
            }
            #pragma unroll
            for (int mt = 0; mt < 4; ++mt)
                #pragma unroll
                for (int nt = 0; nt < 4; ++nt)
                    acc[mt][nt] = __builtin_amdgcn_mfma_f32_16x16x32_bf16(
                        af[mt], bfr[nt], acc[mt][nt], 0, 0, 0);
        }
        __syncthreads();
    }
    #pragma unroll
    for (int mt = 0; mt < 4; ++mt)
        #pragma unroll
        for (int nt = 0; nt < 4; ++nt) {
            int col = bn * 128 + wc * 64 + nt * 16 + l16;
            #pragma unroll
            for (int j = 0; j < 4; ++j) {
                int rowg = bm * 128 + wr * 64 + mt * 16 + lhi * 4 + j;
                part[(size_t)blockIdx.y * M * N + (size_t)rowg * N + col] = acc[mt][nt][j];
            }
        }
}

// ---------------------------------------------------------------------------
// 8-wave 256x128 GEMM, single-buffered (for multi-block/CU grids: qproj3).
// ---------------------------------------------------------------------------
template <typename CT>
__global__ __launch_bounds__(512) void gemm256(
    const bf* __restrict__ A, int lda,
    const bf* __restrict__ B, int ldb,
    const float* __restrict__ bias,
    CT* __restrict__ C, int ldc,
    int M, int N, int K)
{
    __shared__ short As[256 * 64];
    __shared__ short Bs[128 * 64];
    const int nbn = N >> 7;
    int bid = blockIdx.x;
    bid = (bid & 7) * (gridDim.x >> 3) + (bid >> 3);
    const int bm = bid / nbn, bn = bid % nbn;
    const int t = threadIdx.x;
    const int w = t >> 6, lane = t & 63;
    const int wr = w >> 1, wc = w & 1;
    const int l16 = lane & 15, lhi = lane >> 4;

    f32x4 acc[4][4];
    #pragma unroll
    for (int i = 0; i < 4; ++i)
        #pragma unroll
        for (int j = 0; j < 4; ++j) { f32x4 z = {0.f, 0.f, 0.f, 0.f}; acc[i][j] = z; }

    const bf* Arow = A + (size_t)bm * 256 * lda;
    const bf* Brow = B + (size_t)bn * 128 * ldb;

    for (int k0 = 0; k0 < K; k0 += 64) {
        #pragma unroll
        for (int j = 0; j < 2; ++j) {
            int u = t + (j << 9);
            int row = u >> 3, c8 = u & 7;
            int slot = c8 ^ (row & 7);
            GLOAD_LDS16(Brow + (size_t)row * ldb + k0 + slot * 8, &Bs[(j * 8 + w) * 512]);
        }
        #pragma unroll
        for (int j = 0; j < 4; ++j) {
            int u = t + (j << 9);
            int row = u >> 3, c8 = u & 7;
            int slot = c8 ^ (row & 7);
            GLOAD_LDS16(Arow + (size_t)row * lda + k0 + slot * 8, &As[(j * 8 + w) * 512]);
        }
        __syncthreads();
        #pragma unroll
        for (int kk = 0; kk < 2; ++kk) {
            short8v af[4], bfr[4];
            #pragma unroll
            for (int mt = 0; mt < 4; ++mt) {
                int row = wr * 64 + mt * 16 + l16;
                int slot = (kk * 4 + lhi) ^ (row & 7);
                af[mt] = *(const short8v*)&As[row * 64 + slot * 8];
            }
            #pragma unroll
            for (int nt = 0; nt < 4; ++nt) {
                int row = wc * 64 + nt * 16 + l16;
                int slot = (kk * 4 + lhi) ^ (row & 7);
                bfr[nt] = *(const short8v*)&Bs[row * 64 + slot * 8];
            }
            #pragma unroll
            for (int mt = 0; mt < 4; ++mt)
                #pragma unroll
                for (int nt = 0; nt < 4; ++nt)
                    acc[mt][nt] = __builtin_amdgcn_mfma_f32_16x16x32_bf16(
                        af[mt], bfr[nt], acc[mt][nt], 0, 0, 0);
        }
        __syncthreads();
    }
    #pragma unroll
    for (int mt = 0; mt < 4; ++mt)
        #pragma unroll
        for (int nt = 0; nt < 4; ++nt) {
            int col = bn * 128 + wc * 64 + nt * 16 + l16;
            float bv = bias ? bias[col] : 0.0f;
            #pragma unroll
            for (int j = 0; j < 4; ++j) {
                int rowg = bm * 256 + wr * 64 + mt * 16 + lhi * 4 + j;
                storeC(&C[(size_t)rowg * ldc + col], acc[mt][nt][j] + bv);
            }
        }
}

// ---------------------------------------------------------------------------
// 8-wave 256x128 GEMM, DOUBLE-BUFFERED 2-phase (for 1-block/CU grids: tail).
// Named buffers, raw s_barrier + counted asm vmcnt(6). K multiple of 128.
// ---------------------------------------------------------------------------
template <typename CT>
__global__ __launch_bounds__(512) void gemm256db(
    const bf* __restrict__ A, int lda,
    const bf* __restrict__ B, int ldb,
    const float* __restrict__ bias,
    CT* __restrict__ C, int ldc,
    int M, int N, int K)
{
    __shared__ short As0[256 * 64];
    __shared__ short Bs0[128 * 64];
    __shared__ short As1[256 * 64];
    __shared__ short Bs1[128 * 64];
    const int nbn = N >> 7;
    int bid = blockIdx.x;
    bid = (bid & 7) * (gridDim.x >> 3) + (bid >> 3);
    const int bm = bid / nbn, bn = bid % nbn;
    const int t = threadIdx.x;
    const int w = t >> 6, lane = t & 63;
    const int wr = w >> 1, wc = w & 1;
    const int l16 = lane & 15, lhi = lane >> 4;

    f32x4 acc[4][4];
    #pragma unroll
    for (int i = 0; i < 4; ++i)
        #pragma unroll
        for (int j = 0; j < 4; ++j) { f32x4 z = {0.f, 0.f, 0.f, 0.f}; acc[i][j] = z; }

    const bf* Arow = A + (size_t)bm * 256 * lda;
    const bf* Brow = B + (size_t)bn * 128 * ldb;

    auto stage = [&](short* Asd, short* Bsd, int k0) {
        #pragma unroll
        for (int j = 0; j < 2; ++j) {
            int u = t + (j << 9);
            int row = u >> 3, c8 = u & 7;
            int slot = c8 ^ (row & 7);
            GLOAD_LDS16(Brow + (size_t)row * ldb + k0 + slot * 8, &Bsd[(j * 8 + w) * 512]);
        }
        #pragma unroll
        for (int j = 0; j < 4; ++j) {
            int u = t + (j << 9);
            int row = u >> 3, c8 = u & 7;
            int slot = c8 ^ (row & 7);
            GLOAD_LDS16(Arow + (size_t)row * lda + k0 + slot * 8, &Asd[(j * 8 + w) * 512]);
        }
    };
    auto compute = [&](const short* Ass, const short* Bss) {
        #pragma unroll
        for (int kk = 0; kk < 2; ++kk) {
            short8v af[4], bfr[4];
            #pragma unroll
            for (int mt = 0; mt < 4; ++mt) {
                int row = wr * 64 + mt * 16 + l16;
                int slot = (kk * 4 + lhi) ^ (row & 7);
                af[mt] = *(const short8v*)&Ass[row * 64 + slot * 8];
            }
            #pragma unroll
            for (int nt = 0; nt < 4; ++nt) {
                int row = wc * 64 + nt * 16 + l16;
                int slot = (kk * 4 + lhi) ^ (row & 7);
                bfr[nt] = *(const short8v*)&Bss[row * 64 + slot * 8];
            }
            #pragma unroll
            for (int mt = 0; mt < 4; ++mt)
                #pragma unroll
                for (int nt = 0; nt < 4; ++nt)
                    acc[mt][nt] = __builtin_amdgcn_mfma_f32_16x16x32_bf16(
                        af[mt], bfr[nt], acc[mt][nt], 0, 0, 0);
        }
    };

    const int nt_ = K >> 6;
    stage(As0, Bs0, 0);
    stage(As1, Bs1, 64);
    asm volatile("s_waitcnt vmcnt(6)" ::: "memory");
    __builtin_amdgcn_sched_barrier(0);
    __builtin_amdgcn_s_barrier();

    for (int ti = 0; ti < nt_ - 2; ti += 2) {
        compute(As0, Bs0);
        __builtin_amdgcn_s_barrier();
        stage(As0, Bs0, (ti + 2) << 6);
        asm volatile("s_waitcnt vmcnt(6)" ::: "memory");
        __builtin_amdgcn_sched_barrier(0);
        __builtin_amdgcn_s_barrier();
        compute(As1, Bs1);
        __builtin_amdgcn_s_barrier();
        stage(As1, Bs1, (ti + 3) << 6);
        asm volatile("s_waitcnt vmcnt(6)" ::: "memory");
        __builtin_amdgcn_sched_barrier(0);
        __builtin_amdgcn_s_barrier();
    }
    compute(As0, Bs0);
    __builtin_amdgcn_s_barrier();
    asm volatile("s_waitcnt vmcnt(0)" ::: "memory");
    __builtin_amdgcn_sched_barrier(0);
    __builtin_amdgcn_s_barrier();
    compute(As1, Bs1);

    #pragma unroll
    for (int mt = 0; mt < 4; ++mt)
        #pragma unroll
        for (int nt = 0; nt < 4; ++nt) {
            int col = bn * 128 + wc * 64 + nt * 16 + l16;
            float bv = bias ? bias[col] : 0.0f;
            #pragma unroll
            for (int j = 0; j < 4; ++j) {
                int rowg = bm * 256 + wr * 64 + mt * 16 + lhi * 4 + j;
                storeC(&C[(size_t)rowg * ldc + col], acc[mt][nt][j] + bv);
            }
        }
}

// ---------------------------------------------------------------------------
// Grouped GEMM, 7 problems, K=1024, bf16 both sides, DOUBLE-BUFFERED 2-phase
// (grid 256 = 1 block/CU -> dbuf rule applies). vmcnt(8): 8 loads/thread/stage.
// Fused epilogue: bf16 out (+f32 bias), strided ldo.
// ---------------------------------------------------------------------------
struct GG { const bf* A; const bf* B; const float* bias; bf* out;
            int lda, ldb, M, N, ldo, xoff; };
struct GG7 { GG g[7]; };

__global__ __launch_bounds__(256) void ggemm(GG7 P)
{
    __shared__ short As0[128 * 64];
    __shared__ short Bs0[128 * 64];
    __shared__ short As1[128 * 64];
    __shared__ short Bs1[128 * 64];
    const int bid = blockIdx.x;
    int gidx = 0;
    #pragma unroll
    for (int i = 1; i < 7; ++i) if (bid >= P.g[i].xoff) gidx = i;
    const GG d = P.g[gidx];
    const int lb = bid - d.xoff;
    const int nbn = d.N >> 7;
    const int bm = lb / nbn, bn = lb % nbn;
    const int t = threadIdx.x;
    const int w = t >> 6, lane = t & 63;
    const int wr = w >> 1, wc = w & 1;
    const int l16 = lane & 15, lhi = lane >> 4;

    f32x4 acc[4][4];
    #pragma unroll
    for (int i = 0; i < 4; ++i)
        #pragma unroll
        for (int j = 0; j < 4; ++j) { f32x4 z = {0.f, 0.f, 0.f, 0.f}; acc[i][j] = z; }

    const bf* Afrow = d.A + (size_t)bm * 128 * d.lda;
    const bf* Brow  = d.B + (size_t)bn * 128 * d.ldb;

    auto stage = [&](short* Asd, short* Bsd, int k0) {
        #pragma unroll
        for (int j = 0; j < 4; ++j) {
            int u = (w * 4 + j) * 64 + lane;
            int row = u >> 3, c8 = u & 7;
            int slot = c8 ^ (row & 7);
            GLOAD_LDS16(Brow + (size_t)row * d.ldb + k0 + slot * 8, &Bsd[(w * 4 + j) * 512]);
            GLOAD_LDS16(Afrow + (size_t)row * d.lda + k0 + slot * 8, &Asd[(w * 4 + j) * 512]);
        }
    };
    auto compute = [&](const short* Ass, const short* Bss) {
        #pragma unroll
        for (int kk = 0; kk < 2; ++kk) {
            short8v af[4], bfr[4];
            #pragma unroll
            for (int mt = 0; mt < 4; ++mt) {
                int row = wr * 64 + mt * 16 + l16;
                int slot = (kk * 4 + lhi) ^ (row & 7);
                af[mt] = *(const short8v*)&Ass[row * 64 + slot * 8];
            }
            #pragma unroll
            for (int nt = 0; nt < 4; ++nt) {
                int row = wc * 64 + nt * 16 + l16;
                int slot = (kk * 4 + lhi) ^ (row & 7);
                bfr[nt] = *(const short8v*)&Bss[row * 64 + slot * 8];
            }
            #pragma unroll
            for (int mt = 0; mt < 4; ++mt)
                #pragma unroll
                for (int nt = 0; nt < 4; ++nt)
                    acc[mt][nt] = __builtin_amdgcn_mfma_f32_16x16x32_bf16(
                        af[mt], bfr[nt], acc[mt][nt], 0, 0, 0);
        }
    };

    // K = 1024 -> 16 K-tiles
    stage(As0, Bs0, 0);
    stage(As1, Bs1, 64);
    asm volatile("s_waitcnt vmcnt(8)" ::: "memory");
    __builtin_amdgcn_sched_barrier(0);
    __builtin_amdgcn_s_barrier();

    for (int ti = 0; ti < 14; ti += 2) {
        compute(As0, Bs0);
        __builtin_amdgcn_s_barrier();
        stage(As0, Bs0, (ti + 2) << 6);
        asm volatile("s_waitcnt vmcnt(8)" ::: "memory");
        __builtin_amdgcn_sched_barrier(0);
        __builtin_amdgcn_s_barrier();
        compute(As1, Bs1);
        __builtin_amdgcn_s_barrier();
        stage(As1, Bs1, (ti + 3) << 6);
        asm volatile("s_waitcnt vmcnt(8)" ::: "memory");
        __builtin_amdgcn_sched_barrier(0);
        __builtin_amdgcn_s_barrier();
    }
    compute(As0, Bs0);
    __builtin_amdgcn_s_barrier();
    asm volatile("s_waitcnt vmcnt(0)" ::: "memory");
    __builtin_amdgcn_sched_barrier(0);
    __builtin_amdgcn_s_barrier();
    compute(As1, Bs1);

    #pragma unroll
    for (int mt = 0; mt < 4; ++mt)
        #pragma unroll
        for (int nt = 0; nt < 4; ++nt) {
            int col = bn * 128 + wc * 64 + nt * 16 + l16;
            float bv = d.bias ? d.bias[col] : 0.0f;
            #pragma unroll
            for (int j = 0; j < 4; ++j) {
                int rowg = bm * 128 + wr * 64 + mt * 16 + lhi * 4 + j;
                d.out[(size_t)rowg * d.ldo + col]
                    = __float2bfloat16(acc[mt][nt][j] + bv);
            }
        }
}

// ---------------------------------------------------------------------------
// Merged e/s attention, IN-PLACE over qcat3/Ocat [8192,3072].
// ---------------------------------------------------------------------------
__global__ __launch_bounds__(512) void attn_es(
    bf* Ocat, const bf* __restrict__ khE, const bf* __restrict__ khS,
    const bf* __restrict__ vTE, const bf* __restrict__ vTS)
{
    __shared__ short Ks[256 * 64];  // reused as P after QK barrier
    __shared__ short Vs[64 * 256];
    const int bank = blockIdx.x >> 10;
    const int lbid = blockIdx.x & 1023;
    const bf* kh  = bank ? khS : khE;
    const bf* vhT = bank ? vTS : vTE;
    bf* QO = Ocat + bank * 1024;
    const int qt = lbid >> 4, head = lbid & 15;
    const int t = threadIdx.x, w = t >> 6, lane = t & 63;
    const int l16 = lane & 15, lhi = lane >> 4;
    const float scale = 0.125f;

    #pragma unroll
    for (int j = 0; j < 4; ++j) {
        int ublk = w * 4 + j;
        int u = ublk * 64 + lane;
        { int row = u >> 3, c8 = u & 7;
          int slot = c8 ^ (row & 7);
          GLOAD_LDS16(kh + (size_t)row * 1024 + head * 64 + slot * 8, &Ks[ublk * 512]); }
        { int row = u >> 5, c16 = u & 31;
          int slot = c16 ^ (row & 7);
          GLOAD_LDS16(vhT + (size_t)(head * 64 + row) * 256 + slot * 8, &Vs[ublk * 512]); }
    }
    const int qr = qt * 128 + w * 16 + l16;
    short8v aq0 = *(const short8v*)(QO + (size_t)qr * 3072 + head * 64 + lhi * 8);
    short8v aq1 = *(const short8v*)(QO + (size_t)qr * 3072 + head * 64 + 32 + lhi * 8);
    __syncthreads();

    f32x4 sc[16];
    #pragma unroll
    for (int nt = 0; nt < 16; ++nt) { f32x4 z = {0.f, 0.f, 0.f, 0.f}; sc[nt] = z; }
    #pragma unroll
    for (int nt = 0; nt < 16; ++nt) {
        int row = nt * 16 + l16;
        #pragma unroll
        for (int kk = 0; kk < 2; ++kk) {
            int slot = (kk * 4 + lhi) ^ (row & 7);
            short8v b = *(const short8v*)&Ks[row * 64 + slot * 8];
            sc[nt] = __builtin_amdgcn_mfma_f32_16x16x32_bf16(kk ? aq1 : aq0, b, sc[nt], 0, 0, 0);
        }
    }
    float inv[4];
    #pragma unroll
    for (int j = 0; j < 4; ++j) {
        float m_ = -1e30f;
        #pragma unroll
        for (int nt = 0; nt < 16; ++nt) m_ = fmaxf(m_, sc[nt][j]);
        #pragma unroll
        for (int off = 8; off; off >>= 1) m_ = fmaxf(m_, __shfl_xor(m_, off));
        float s_ = 0.f;
        #pragma unroll
        for (int nt = 0; nt < 16; ++nt) {
            float e = __expf((sc[nt][j] - m_) * scale);
            sc[nt][j] = e; s_ += e;
        }
        #pragma unroll
        for (int off = 8; off; off >>= 1) s_ += __shfl_xor(s_, off);
        inv[j] = 1.0f / s_;
    }
    __syncthreads();

    char* Pw = (char*)Ks + w * 4096;
    f32x4 oa[4];
    #pragma unroll
    for (int nt = 0; nt < 4; ++nt) { f32x4 z = {0.f, 0.f, 0.f, 0.f}; oa[nt] = z; }
    #pragma unroll
    for (int h = 0; h < 2; ++h) {
        #pragma unroll
        for (int nt = 0; nt < 8; ++nt) {
            int colL = nt * 16 + l16;
            #pragma unroll
            for (int j = 0; j < 4; ++j) {
                int row = lhi * 4 + j;
                *(short*)(Pw + row * 256 + ((colL * 2) ^ ((row & 7) << 4)))
                    = (short)f2bu(sc[h * 8 + nt][j] * inv[j]);
            }
        }
        #pragma unroll
        for (int kk = 0; kk < 4; ++kk) {
            short8v a = *(const short8v*)(Pw + l16 * 256 + (((kk * 32 + lhi * 8) * 2) ^ ((l16 & 7) << 4)));
            #pragma unroll
            for (int nt = 0; nt < 4; ++nt) {
                int row = nt * 16 + l16;
                int m = h * 128 + kk * 32 + lhi * 8;
                short8v b = *(const short8v*)((const char*)Vs + row * 512 + ((m * 2) ^ ((row & 7) << 4)));
                oa[nt] = __builtin_amdgcn_mfma_f32_16x16x32_bf16(a, b, oa[nt], 0, 0, 0);
            }
        }
    }
    #pragma unroll
    for (int nt = 0; nt < 4; ++nt)
        #pragma unroll
        for (int j = 0; j < 4; ++j)
            QO[(size_t)(qt * 128 + w * 16 + lhi * 4 + j) * 3072 + head * 64 + nt * 16 + l16]
                = __float2bfloat16(oa[nt][j]);
}

// ---------------------------------------------------------------------------
// Working-memory attention, IN-PLACE, 4 rows/block, reg-preloaded K/V.
// ---------------------------------------------------------------------------
__global__ __launch_bounds__(256) void attn_w(
    bf* QOp, const bf* __restrict__ khw, const bf* __restrict__ vhw)
{
    const int t = threadIdx.x;
    const int head = t >> 5;
    const int dg = head * 128 + (t & 31) * 4;

    ushort4 kv[10], vv[10];
    #pragma unroll
    for (int m = 0; m < 10; ++m) {
        kv[m] = *(const ushort4*)(khw + (size_t)m * 1024 + dg);
        vv[m] = *(const ushort4*)(vhw + (size_t)m * 1024 + dg);
    }
    #pragma unroll
    for (int r = 0; r < 4; ++r) {
        const int bs = blockIdx.x * 4 + r;
        ushort4 qv = *(const ushort4*)(QOp + (size_t)bs * 3072 + dg);
        float q0 = bf2f(qv.x), q1 = bf2f(qv.y), q2 = bf2f(qv.z), q3 = bf2f(qv.w);
        float s[10];
        #pragma unroll
        for (int m = 0; m < 10; ++m) {
            float pr = q0 * bf2f(kv[m].x) + q1 * bf2f(kv[m].y)
                     + q2 * bf2f(kv[m].z) + q3 * bf2f(kv[m].w);
            #pragma unroll
            for (int off = 16; off; off >>= 1) pr += __shfl_xor(pr, off);
            s[m] = pr * 0.08838834764831845f;
        }
        float mx = s[0];
        #pragma unroll
        for (int m = 1; m < 10; ++m) mx = fmaxf(mx, s[m]);
        float pp[10], sum = 0.f;
        #pragma unroll
        for (int m = 0; m < 10; ++m) { pp[m] = __expf(s[m] - mx); sum += pp[m]; }
        float inv = 1.0f / sum;
        float o0 = 0, o1 = 0, o2 = 0, o3 = 0;
        #pragma unroll
        for (int m = 0; m < 10; ++m) {
            o0 += pp[m] * bf2f(vv[m].x); o1 += pp[m] * bf2f(vv[m].y);
            o2 += pp[m] * bf2f(vv[m].z); o3 += pp[m] * bf2f(vv[m].w);
        }
        bf* op = QOp + (size_t)bs * 3072 + dg;
        op[0] = __float2bfloat16(o0 * inv); op[1] = __float2bfloat16(o1 * inv);
        op[2] = __float2bfloat16(o2 * inv); op[3] = __float2bfloat16(o3 * inv);
    }
}

// ---------------------------------------------------------------------------
// MEGAPREP: one launch for all independent prep work.
// blocks [0,20224): 13-segment f32->bf16 cvt (q->qb, pw->pwb in d_out alias)
//        [20224,21248): 4x 1024x1024 transpose+cvt
//        [21248,22016): bprime (3072 wave-dots)
//        [22016,22028): gather3 (bqcat3, 3072)
//        [22028,27148): khvw (20480 wave-dots)
// ---------------------------------------------------------------------------
struct CS { const float* src; bf* dst; int voff; };
struct MP {
    CS cs[13];
    const float* tsrc[4]; bf* tdst[4];
    const float* ow[3]; const float* ob[3]; const float* ib[3];
    float* bp;
    const float* inb_e; const float* inb_s; float* bqcat3;
    const float* wm; const float* inw_w; const float* inb_w;
    bf* khw; bf* vhw;
};

__global__ __launch_bounds__(256) void megaprep(MP P)
{
    __shared__ unsigned short tile[64][65];
    const int bid = blockIdx.x;
    const int t = threadIdx.x;
    if (bid < 20224) {
        int gi = bid * 256 + t;
        int gidx = 0;
        #pragma unroll
        for (int i = 1; i < 13; ++i) if (gi >= P.cs[i].voff) gidx = i;
        int i = (gi - P.cs[gidx].voff) * 4;
        float4 v = *(const float4*)(P.cs[gidx].src + i);
        ushort4 o;
        o.x = f2bu(v.x); o.y = f2bu(v.y); o.z = f2bu(v.z); o.w = f2bu(v.w);
        *(ushort4*)((unsigned short*)P.cs[gidx].dst + i) = o;
    } else if (bid < 21248) {
        int lb = bid - 20224;
        int sel = lb >> 8, bb = lb & 255;
        const float* in = P.tsrc[sel];
        bf* outT = P.tdst[sel];
        int bx = bb & 15, by = bb >> 4;
        int r0 = by * 64, c0 = bx * 64;
        int tr = t >> 4, tc4 = (t & 15) * 4;
        #pragma unroll
        for (int i = 0; i < 4; ++i) {
            int r = tr + i * 16;
            float4 v = *(const float4*)(in + (size_t)(r0 + r) * 1024 + c0 + tc4);
            tile[r][tc4 + 0] = f2bu(v.x); tile[r][tc4 + 1] = f2bu(v.y);
            tile[r][tc4 + 2] = f2bu(v.z); tile[r][tc4 + 3] = f2bu(v.w);
        }
        __syncthreads();
        #pragma unroll
        for (int i = 0; i < 4; ++i) {
            int r = tr + i * 16;
            ushort4 v;
            v.x = tile[tc4 + 0][r]; v.y = tile[tc4 + 1][r];
            v.z = tile[tc4 + 2][r]; v.w = tile[tc4 + 3][r];
            *(ushort4*)((unsigned short*)outT + (size_t)(c0 + r) * 1024 + r0 + tc4) = v;
        }
    } else if (bid < 22016) {
        int g = (bid - 21248) * 4 + (t >> 6);
        int lane = t & 63;
        int bank = g >> 10, j = g & 1023;
        const float* ow = P.ow[bank];
        const float* xx = P.ib[bank] + 2048;
        const float* wrow = ow + (size_t)j * 1024;
        float acc = 0.f;
        #pragma unroll
        for (int cc = 0; cc < 4; ++cc) {
            float4 a = *(const float4*)(wrow + lane * 16 + cc * 4);
            float4 x = *(const float4*)(xx + lane * 16 + cc * 4);
            acc += a.x * x.x + a.y * x.y + a.z * x.z + a.w * x.w;
        }
        #pragma unroll
        for (int off = 32; off; off >>= 1) acc += __shfl_xor(acc, off);
        if (lane == 0) P.bp[g] = acc + P.ob[bank][j];
    } else if (bid < 22028) {
        int i = (bid - 22016) * 256 + t;
        if (i < 1024) P.bqcat3[i] = P.inb_e[i];
        else if (i < 2048) P.bqcat3[i] = P.inb_s[i - 1024];
        else P.bqcat3[i] = P.inb_w[i - 2048];
    } else {
        int o = (bid - 22028) * 4 + (t >> 6);
        int lane = t & 63;
        int sel = o >= 10240;
        int o2 = o - sel * 10240;
        int m = o2 >> 10, c = o2 & 1023;
        const float* wrow = P.inw_w + (size_t)(1024 + sel * 1024 + c) * 1024;
        const float* xrow = P.wm + (size_t)m * 1024;
        float acc = 0.f;
        #pragma unroll
        for (int cc = 0; cc < 4; ++cc) {
            float4 a = *(const float4*)(wrow + lane * 16 + cc * 4);
            float4 x = *(const float4*)(xrow + lane * 16 + cc * 4);
            acc += a.x * x.x + a.y * x.y + a.z * x.z + a.w * x.w;
        }
        #pragma unroll
        for (int off = 32; off; off >>= 1) acc += __shfl_xor(acc, off);
        if (lane == 0) {
            float v = acc + (sel ? 0.f : P.inb_w[1024 + c]);
            (sel ? P.vhw : P.khw)[(size_t)m * 1024 + c] = __float2bfloat16(v);
        }
    }
}

// --------------------------- remaining small kernels ------------------------

__global__ __launch_bounds__(256) void btot_kern(
    const float* __restrict__ bp, const float* __restrict__ pw,
    const float* __restrict__ pb, float* __restrict__ btot)
{
    int j = blockIdx.x * 4 + (threadIdx.x >> 6);
    int lane = threadIdx.x & 63;
    const float* row = pw + (size_t)j * 3072;
    float acc = 0.f;
    #pragma unroll
    for (int it = 0; it < 12; ++it) {
        int c = lane * 4 + it * 256;
        float4 a = *(const float4*)(row + c);
        float4 x = *(const float4*)(bp + c);
        acc += a.x * x.x + a.y * x.y + a.z * x.z + a.w * x.w;
    }
    #pragma unroll
    for (int off = 32; off; off >>= 1) acc += __shfl_xor(acc, off);
    if (lane == 0) btot[j] = acc + pb[j];
}

// reduce 8 S1 partials + softmax + x0.1 -> wT[m][n] (bf16, transposed)
__global__ __launch_bounds__(256) void write_softmax_p(const float* __restrict__ part,
                                                       bf* __restrict__ wT)
{
    const int n = blockIdx.x, m = threadIdx.x;
    float s = 0.f;
    #pragma unroll
    for (int k = 0; k < 8; ++k) s += part[(size_t)k * 262144 + n * 256 + m];
    float mx = s;
    #pragma unroll
    for (int off = 32; off; off >>= 1) mx = fmaxf(mx, __shfl_xor(mx, off));
    __shared__ float red[4], red2[4];
    int w = threadIdx.x >> 6;
    if ((threadIdx.x & 63) == 0) red[w] = mx;
    __syncthreads();
    mx = fmaxf(fmaxf(red[0], red[1]), fmaxf(red[2], red[3]));
    float e = __expf(s - mx);
    float sm = e;
    #pragma unroll
    for (int off = 32; off; off >>= 1) sm += __shfl_xor(sm, off);
    if ((threadIdx.x & 63) == 0) red2[w] = sm;
    __syncthreads();
    sm = red2[0] + red2[1] + red2[2] + red2[3];
    wT[(size_t)m * 1024 + n] = __float2bfloat16(0.1f * e / sm);
}

// FUSED: u[m] reduction from wT row + 8-way writes-partials reduce + update.
__global__ __launch_bounds__(256) void update_fused(
    const float* __restrict__ epk, const float* __restrict__ epv,
    const bf* __restrict__ wT, const float* __restrict__ part,
    bf* __restrict__ ekb, bf* __restrict__ evb)
{
    __shared__ float red[4];
    const int m = blockIdx.x, t = threadIdx.x;
    ushort4 wv = *(const ushort4*)((const unsigned short*)wT + (size_t)m * 1024 + t * 4);
    float s = bf2f(wv.x) + bf2f(wv.y) + bf2f(wv.z) + bf2f(wv.w);
    #pragma unroll
    for (int off = 32; off; off >>= 1) s += __shfl_xor(s, off);
    if ((t & 63) == 0) red[t >> 6] = s;
    __syncthreads();
    float f = 1.0f - (red[0] + red[1] + red[2] + red[3]) * (1.0f / 1024.0f);
    int base = m * 1024 + t * 4;
    float4 wr = *(const float4*)(part + base);
    #pragma unroll
    for (int k = 1; k < 8; ++k) {
        float4 v = *(const float4*)(part + (size_t)k * 262144 + base);
        wr.x += v.x; wr.y += v.y; wr.z += v.z; wr.w += v.w;
    }
    const float sc = 1.0f / 1024.0f;
    float4 pk = *(const float4*)(epk + base);
    float4 pv = *(const float4*)(epv + base);
    ushort4 ok, ov;
    ok.x = f2bu(pk.x * f + wr.x * sc); ok.y = f2bu(pk.y * f + wr.y * sc);
    ok.z = f2bu(pk.z * f + wr.z * sc); ok.w = f2bu(pk.w * f + wr.w * sc);
    ov.x = f2bu(pv.x * f + wr.x * sc); ov.y = f2bu(pv.y * f + wr.y * sc);
    ov.z = f2bu(pv.z * f + wr.z * sc); ov.w = f2bu(pv.w * f + wr.w * sc);
    *(ushort4*)((unsigned short*)ekb + base) = ok;
    *(ushort4*)((unsigned short*)evb + base) = ov;
}

// ---------------------------------------------------------------------------
extern "C" void kernel_launch(void* const* d_in, const int* in_sizes, int n_in,
                              void* d_out, int out_size, void* d_ws, size_t ws_size,
                              hipStream_t stream)
{
    const float* q     = (const float*)d_in[0];
    const float* data  = (const float*)d_in[1];
    const float* epk   = (const float*)d_in[2];
    const float* epv   = (const float*)d_in[3];
    const float* smk   = (const float*)d_in[4];
    const float* smv   = (const float*)d_in[5];
    const float* wm    = (const float*)d_in[6];
    const float* inw_e = (const float*)d_in[7];  const float* inb_e = (const float*)d_in[8];
    const float* ow_e  = (const float*)d_in[9];  const float* ob_e  = (const float*)d_in[10];
    const float* inw_s = (const float*)d_in[11]; const float* inb_s = (const float*)d_in[12];
    const float* ow_s  = (const float*)d_in[13]; const float* ob_s  = (const float*)d_in[14];
    const float* inw_w = (const float*)d_in[15]; const float* inb_w = (const float*)d_in[16];
    const float* ow_w  = (const float*)d_in[17]; const float* ob_w  = (const float*)d_in[18];
    const float* pw    = (const float*)d_in[19]; const float* pb    = (const float*)d_in[20];
    float* out  = (float*)d_out;
    float* part = (float*)d_out;                       // write-phase partials [0, 8.4 MB)
    bf* qb  = (bf*)((char*)d_out + 8388608);           // q bf16 [8.4, 25.2 MB)
    bf* pwb = (bf*)((char*)d_out + 25165824);          // pw bf16 [25.2, 31.5 MB)

    char* p = (char*)d_ws;
    auto alloc = [&](size_t bytes) -> char* {
        char* r = p; p += (bytes + 255) & ~(size_t)255; return r;
    };
    float* bp     = (float*)alloc(3072 * 4);
    float* btot   = (float*)alloc(1024 * 4);
    float* bqcat3 = (float*)alloc(3072 * 4);
    bf* wT     = (bf*)alloc(256 * 1024 * 2);
    bf* dT     = (bf*)alloc((size_t)1024 * 1024 * 2);
    bf* datab  = (bf*)alloc((size_t)1024 * 1024 * 2);
    bf* epkb   = (bf*)alloc(256 * 1024 * 2);
    bf* smkb   = (bf*)alloc(256 * 1024 * 2);
    bf* smvb   = (bf*)alloc(256 * 1024 * 2);
    bf* ekb    = (bf*)alloc(256 * 1024 * 2);
    bf* evb    = (bf*)alloc(256 * 1024 * 2);
    bf* khE    = (bf*)alloc(256 * 1024 * 2);
    bf* khS    = (bf*)alloc(256 * 1024 * 2);
    bf* vTE    = (bf*)alloc((size_t)1024 * 256 * 2);
    bf* vTS    = (bf*)alloc((size_t)1024 * 256 * 2);
    bf* khw    = (bf*)alloc(10 * 1024 * 2);
    bf* vhw    = (bf*)alloc(10 * 1024 * 2);
    bf* Wall   = (bf*)alloc((size_t)3072 * 1024 * 2); // [Wq_e; Wq_s; Wq_w]
    bf* WkE    = (bf*)alloc((size_t)1024 * 1024 * 2);
    bf* WkS    = (bf*)alloc((size_t)1024 * 1024 * 2);
    bf* WvE    = (bf*)alloc((size_t)1024 * 1024 * 2);
    bf* WvS    = (bf*)alloc((size_t)1024 * 1024 * 2);
    bf* owT0   = (bf*)alloc((size_t)1024 * 1024 * 2);
    bf* owT1   = (bf*)alloc((size_t)1024 * 1024 * 2);
    bf* owT2   = (bf*)alloc((size_t)1024 * 1024 * 2);
    bf* Gcat   = (bf*)alloc((size_t)1024 * 3072 * 2);
    bf* Ocat   = (bf*)alloc((size_t)8192 * 3072 * 2); // qcat3 -> attn in-place -> tail A
    if ((size_t)(p - (char*)d_ws) > ws_size) return;

    // ---- launch 1: megaprep ----
    {
        MP P;
        CS cs[13] = { {q, qb, 0},
                      {epk,  epkb, 2097152}, {smv, smvb, 2162688},
                      {inw_e, Wall, 2228224},
                      {inw_s, Wall + (size_t)1024 * 1024, 2490368},
                      {inw_w, Wall + (size_t)2048 * 1024, 2752512},
                      {inw_e + (size_t)1024 * 1024, WkE, 3014656},
                      {inw_s + (size_t)1024 * 1024, WkS, 3276800},
                      {data, datab, 3538944},
                      {pw, pwb, 3801088},
                      {smk, smkb, 4587520},
                      {inw_e + (size_t)2048 * 1024, WvE, 4653056},
                      {inw_s + (size_t)2048 * 1024, WvS, 4915200} };
        for (int i = 0; i < 13; ++i) P.cs[i] = cs[i];
        P.tsrc[0] = data; P.tdst[0] = dT;
        P.tsrc[1] = ow_e; P.tdst[1] = owT0;
        P.tsrc[2] = ow_s; P.tdst[2] = owT1;
        P.tsrc[3] = ow_w; P.tdst[3] = owT2;
        P.ow[0] = ow_e; P.ow[1] = ow_s; P.ow[2] = ow_w;
        P.ob[0] = ob_e; P.ob[1] = ob_s; P.ob[2] = ob_w;
        P.ib[0] = inb_e; P.ib[1] = inb_s; P.ib[2] = inb_w;
        P.bp = bp;
        P.inb_e = inb_e; P.inb_s = inb_s; P.bqcat3 = bqcat3;
        P.wm = wm; P.inw_w = inw_w; P.inb_w = inb_w;
        P.khw = khw; P.vhw = vhw;
        megaprep<<<27148, 256, 0, stream>>>(P);
    }
    // ---- launch 2: btot (needs bp) ----
    btot_kern<<<256, 256, 0, stream>>>(bp, pw, pb, btot);

    // ---- write phase (partials in d_out[0, 8.4 MB)) ----
    gemm_bt<<<dim3(16, 8), 256, 0, stream>>>(datab, 1024, epkb, 1024, part, 1024, 256, 1024);
    write_softmax_p<<<1024, 256, 0, stream>>>(part, wT);
    gemm_bt<<<dim3(16, 8), 256, 0, stream>>>(wT, 1024, dT, 1024, part, 256, 1024, 1024);
    update_fused<<<256, 256, 0, stream>>>(epk, epv, wT, part, ekb, evb);

    // ---- merged q-projection: qcat3 = qb @ Wall^T + bqcat3 -> Ocat ----
    gemm256<bf><<<768, 512, 0, stream>>>(
        qb, 1024, Wall, 1024, bqcat3, Ocat, 3072, 8192, 3072, 1024);

    // ---- grouped GEMM, dbuf 2-phase, bf16 both sides (7 problems) ----
    {
        GG7 G = {{
            { ekb,        WkE,  inb_e + 1024, khE,         1024, 1024,  256, 1024, 1024, 0   },
            { smkb,       WkS,  inb_s + 1024, khS,         1024, 1024,  256, 1024, 1024, 16  },
            { WvE,        evb,  nullptr,      vTE,         1024, 1024, 1024,  256,  256, 32  },
            { WvS,        smvb, nullptr,      vTS,         1024, 1024, 1024,  256,  256, 48  },
            { pwb + 0,    owT0, nullptr,      Gcat + 0,    3072, 1024, 1024, 1024, 3072, 64  },
            { pwb + 1024, owT1, nullptr,      Gcat + 1024, 3072, 1024, 1024, 1024, 3072, 128 },
            { pwb + 2048, owT2, nullptr,      Gcat + 2048, 3072, 1024, 1024, 1024, 3072, 192 },
        }};
        ggemm<<<256, 256, 0, stream>>>(G);
    }

    // ---- attentions, in-place over Ocat ----
    attn_es<<<2048, 512, 0, stream>>>(Ocat, khE, khS, vTE, vTS);
    attn_w<<<2048, 256, 0, stream>>>(Ocat + 2048, khw, vhw);

    // ---- fused tail: double-buffered 2-phase schedule (1 block/CU grid) ----
    gemm256db<float><<<256, 512, 0, stream>>>(
        Ocat, 3072, Gcat, 3072, btot, out, 1024, 8192, 1024, 3072);
}